// Round 1
// baseline (489.132 us; speedup 1.0000x reference)
//
#include <hip/hip_runtime.h>
#include <hip/hip_bf16.h>

#define B_ 2
#define T_ 2048
#define E_ 1024
#define H_ 16
#define HD_ 64
#define NT (B_*T_)

typedef __attribute__((ext_vector_type(8))) short s16x8;
typedef __attribute__((ext_vector_type(4))) float f32x4;
typedef __attribute__((ext_vector_type(4))) unsigned int u32x4;

using bf16 = __hip_bfloat16;

#define MFMA16(a,b,c) __builtin_amdgcn_mfma_f32_16x16x32_bf16(a,b,c,0,0,0)

__device__ inline unsigned short f2bf(float f) {
    bf16 h = __float2bfloat16(f);
    return *reinterpret_cast<unsigned short*>(&h);
}

// ---------------- weight transpose + fp32->bf16 ----------------
// W [K][N] row-major -> Wt [N][K] bf16 row-major
__global__ __launch_bounds__(256) void transpose_cvt(const float* __restrict__ W,
                                                     bf16* __restrict__ Wt,
                                                     int K, int N) {
    __shared__ float tile[32][33];
    int tx = threadIdx.x, ty = threadIdx.y;
    int n0 = blockIdx.x * 32, k0 = blockIdx.y * 32;
#pragma unroll
    for (int i = 0; i < 4; ++i)
        tile[ty + i*8][tx] = W[(size_t)(k0 + ty + i*8)*N + n0 + tx];
    __syncthreads();
#pragma unroll
    for (int i = 0; i < 4; ++i)
        Wt[(size_t)(n0 + ty + i*8)*K + k0 + tx] = __float2bfloat16(tile[tx][ty + i*8]);
}

// ---------------- LayerNorm (fp32 in -> bf16 out) ----------------
__global__ __launch_bounds__(256) void ln_kernel(const float* __restrict__ x,
                                                 const float* __restrict__ g,
                                                 const float* __restrict__ b,
                                                 bf16* __restrict__ h) {
    int row = blockIdx.x;
    int tid = threadIdx.x;
    const float4 xv = *reinterpret_cast<const float4*>(x + (size_t)row*E_ + tid*4);
    float s  = xv.x + xv.y + xv.z + xv.w;
    float sq = xv.x*xv.x + xv.y*xv.y + xv.z*xv.z + xv.w*xv.w;
#pragma unroll
    for (int o = 32; o > 0; o >>= 1) { s += __shfl_xor(s, o); sq += __shfl_xor(sq, o); }
    __shared__ float red[8];
    int w = tid >> 6, lane = tid & 63;
    if (lane == 0) { red[w] = s; red[4 + w] = sq; }
    __syncthreads();
    float S = red[0] + red[1] + red[2] + red[3];
    float Q = red[4] + red[5] + red[6] + red[7];
    float mu = S * (1.0f/E_);
    float var = Q * (1.0f/E_) - mu*mu;
    float rs = rsqrtf(var + 1e-5f);
    const float4 gv = *reinterpret_cast<const float4*>(g + tid*4);
    const float4 bv = *reinterpret_cast<const float4*>(b + tid*4);
    ushort4 o4;
    o4.x = f2bf((xv.x - mu)*rs*gv.x + bv.x);
    o4.y = f2bf((xv.y - mu)*rs*gv.y + bv.y);
    o4.z = f2bf((xv.z - mu)*rs*gv.z + bv.z);
    o4.w = f2bf((xv.w - mu)*rs*gv.w + bv.w);
    *reinterpret_cast<ushort4*>(h + (size_t)row*E_ + tid*4) = o4;
}

// ---------------- 128x128 bf16 MFMA GEMM, C = A @ Bt^T ----------------
// A [M][K] bf16, Bt [N][K] bf16. EPI: 0 = bf16 out; 1 = f32 out + bias + res; 2 = relu(acc+bias) bf16
template<int EPI>
__global__ __launch_bounds__(256)
void gemm128(const bf16* __restrict__ A, const bf16* __restrict__ Bt, void* Cout,
             const float* __restrict__ bias, const float* res,
             int M, int N, int K) {
    __shared__ bf16 As[128*32];
    __shared__ bf16 Bs[128*32];
    int tid = threadIdx.x;
    int lane = tid & 63, w = tid >> 6;
    int wr = w >> 1, wc = w & 1;
    int m0 = blockIdx.y * 128, n0 = blockIdx.x * 128;
    int lr = lane & 15, lq = lane >> 4;
    f32x4 acc[4][4] = {};
    for (int k0 = 0; k0 < K; k0 += 32) {
        u32x4 va[2], vb[2];
#pragma unroll
        for (int i = 0; i < 2; ++i) {
            int c = i*256 + tid;
            int r = c >> 2, cc = c & 3;
            va[i] = *reinterpret_cast<const u32x4*>(A  + (size_t)(m0 + r)*K + k0 + cc*8);
            vb[i] = *reinterpret_cast<const u32x4*>(Bt + (size_t)(n0 + r)*K + k0 + cc*8);
        }
        __syncthreads();
#pragma unroll
        for (int i = 0; i < 2; ++i) {
            int c = i*256 + tid;
            reinterpret_cast<u32x4*>(As)[c] = va[i];
            reinterpret_cast<u32x4*>(Bs)[c] = vb[i];
        }
        __syncthreads();
        s16x8 af[4], bfr[4];
#pragma unroll
        for (int m = 0; m < 4; ++m)
            af[m] = *reinterpret_cast<const s16x8*>(As + (wr*64 + m*16 + lr)*32 + lq*8);
#pragma unroll
        for (int n = 0; n < 4; ++n)
            bfr[n] = *reinterpret_cast<const s16x8*>(Bs + (wc*64 + n*16 + lr)*32 + lq*8);
#pragma unroll
        for (int m = 0; m < 4; ++m)
#pragma unroll
            for (int n = 0; n < 4; ++n)
                acc[m][n] = MFMA16(af[m], bfr[n], acc[m][n]);
    }
#pragma unroll
    for (int m = 0; m < 4; ++m) {
#pragma unroll
        for (int n = 0; n < 4; ++n) {
            int col = n0 + wc*64 + n*16 + lr;
#pragma unroll
            for (int r = 0; r < 4; ++r) {
                int row = m0 + wr*64 + m*16 + lq*4 + r;
                float v = acc[m][n][r];
                if (EPI == 0) {
                    reinterpret_cast<bf16*>(Cout)[(size_t)row*N + col] = __float2bfloat16(v);
                } else if (EPI == 1) {
                    reinterpret_cast<float*>(Cout)[(size_t)row*N + col] =
                        v + bias[col] + res[(size_t)row*N + col];
                } else {
                    v += bias[col];
                    v = v > 0.f ? v : 0.f;
                    reinterpret_cast<bf16*>(Cout)[(size_t)row*N + col] = __float2bfloat16(v);
                }
            }
        }
    }
}

// ---------------- V transpose: qkv v-section -> Vt [B,H,HD,T] ----------------
__global__ __launch_bounds__(256) void v_transpose(const bf16* __restrict__ qkv,
                                                   bf16* __restrict__ Vt) {
    __shared__ unsigned short tile[32][33];
    int tx = threadIdx.x, ty = threadIdx.y;
    int bh = blockIdx.z;
    int b = bh >> 4, h = bh & 15;
    int t0 = blockIdx.x * 32, d0 = blockIdx.y * 32;
    const unsigned short* src = reinterpret_cast<const unsigned short*>(qkv);
#pragma unroll
    for (int i = 0; i < 4; ++i)
        tile[ty + i*8][tx] = src[(size_t)(b*T_ + t0 + ty + i*8)*3072 + 2048 + h*64 + d0 + tx];
    __syncthreads();
    unsigned short* dst = reinterpret_cast<unsigned short*>(Vt);
#pragma unroll
    for (int i = 0; i < 4; ++i)
        dst[(size_t)(bh*64 + d0 + ty + i*8)*T_ + t0 + tx] = tile[tx][ty + i*8];
}

// ---------------- causal flash attention ----------------
// grid (T/64, B*H), 256 threads (4 waves x 16 q-rows). Q,K from qkv; V from Vt.
__global__ __launch_bounds__(256)
void flash_attn(const bf16* __restrict__ qkv, const bf16* __restrict__ Vt,
                bf16* __restrict__ O) {
    int tid = threadIdx.x;
    int lane = tid & 63, w = tid >> 6;
    int lr = lane & 15, lq = lane >> 4;
    int bh = blockIdx.y, b = bh >> 4, h = bh & 15;
    int q0 = blockIdx.x * 64;
    int qw = q0 + w * 16;
    const bf16* Qb = qkv + (size_t)(b*T_)*3072 + h*HD_;
    const bf16* Kb = Qb + 1024;
    const bf16* Vb = Vt + (size_t)bh * HD_ * T_;
    __shared__ char Pl[4][2048];
    s16x8 qf[2];
#pragma unroll
    for (int kk = 0; kk < 2; ++kk)
        qf[kk] = *reinterpret_cast<const s16x8*>(Qb + (size_t)(qw + lr)*3072 + kk*32 + lq*8);
    f32x4 od[4] = {};
    float mrun[4], lrun[4];
#pragma unroll
    for (int r = 0; r < 4; ++r) { mrun[r] = -1e30f; lrun[r] = 0.f; }
    const float SLOG2E = 0.125f * 1.44269504088896f;  // scores pre-multiplied into log2 units
    int ntiles = (q0 >> 6) + 1;
    for (int it = 0; it < ntiles; ++it) {
        int kv0 = it * 64;
        f32x4 sc[4];
#pragma unroll
        for (int n = 0; n < 4; ++n) {
            const bf16* kp = Kb + (size_t)(kv0 + n*16 + lr)*3072 + lq*8;
            s16x8 kf0 = *reinterpret_cast<const s16x8*>(kp);
            s16x8 kf1 = *reinterpret_cast<const s16x8*>(kp + 32);
            f32x4 z = {0.f, 0.f, 0.f, 0.f};
            z = MFMA16(qf[0], kf0, z);
            z = MFMA16(qf[1], kf1, z);
            sc[n] = z;
        }
        bool last = (it == ntiles - 1);
        float tmax[4] = {-1e30f, -1e30f, -1e30f, -1e30f};
#pragma unroll
        for (int n = 0; n < 4; ++n) {
#pragma unroll
            for (int r = 0; r < 4; ++r) {
                float v = sc[n][r] * SLOG2E;
                if (last) {
                    int row = qw + lq*4 + r;
                    int col = kv0 + n*16 + lr;
                    if (col > row) v = -1e30f;
                }
                sc[n][r] = v;
                tmax[r] = fmaxf(tmax[r], v);
            }
        }
#pragma unroll
        for (int r = 0; r < 4; ++r) {
#pragma unroll
            for (int o = 8; o > 0; o >>= 1)
                tmax[r] = fmaxf(tmax[r], __shfl_xor(tmax[r], o));
        }
        float corr[4], psum[4];
#pragma unroll
        for (int r = 0; r < 4; ++r) {
            float mn = fmaxf(mrun[r], tmax[r]);
            corr[r] = exp2f(mrun[r] - mn);
            mrun[r] = mn;
            psum[r] = 0.f;
        }
#pragma unroll
        for (int n = 0; n < 4; ++n) {
#pragma unroll
            for (int r = 0; r < 4; ++r) {
                float p = exp2f(sc[n][r] - mrun[r]);
                psum[r] += p;
                int rowl = lq*4 + r;
                int bo = (rowl*128 + (n*16 + lr)*2) ^ ((rowl & 7) << 4);  // XOR-swizzle (G4)
                *reinterpret_cast<unsigned short*>(&Pl[w][bo]) = f2bf(p);
            }
        }
#pragma unroll
        for (int r = 0; r < 4; ++r) {
#pragma unroll
            for (int o = 8; o > 0; o >>= 1)
                psum[r] += __shfl_xor(psum[r], o);
            lrun[r] = lrun[r]*corr[r] + psum[r];
        }
#pragma unroll
        for (int nd = 0; nd < 4; ++nd)
#pragma unroll
            for (int r = 0; r < 4; ++r)
                od[nd][r] *= corr[r];
        s16x8 pa[2];
#pragma unroll
        for (int kk = 0; kk < 2; ++kk) {
            int bo = (lr*128 + kk*64 + lq*16) ^ ((lr & 7) << 4);
            pa[kk] = *reinterpret_cast<const s16x8*>(&Pl[w][bo]);
        }
#pragma unroll
        for (int nd = 0; nd < 4; ++nd) {
            const bf16* vp = Vb + (size_t)(nd*16 + lr)*T_ + kv0 + lq*8;
            s16x8 vf0 = *reinterpret_cast<const s16x8*>(vp);
            s16x8 vf1 = *reinterpret_cast<const s16x8*>(vp + 32);
            od[nd] = MFMA16(pa[0], vf0, od[nd]);
            od[nd] = MFMA16(pa[1], vf1, od[nd]);
        }
    }
#pragma unroll
    for (int nd = 0; nd < 4; ++nd) {
#pragma unroll
        for (int r = 0; r < 4; ++r) {
            int row = qw + lq*4 + r;
            float v = od[nd][r] / lrun[r];
            O[(size_t)(b*T_ + row)*E_ + h*HD_ + nd*16 + lr] = __float2bfloat16(v);
        }
    }
}

// ---------------- launch ----------------
extern "C" void kernel_launch(void* const* d_in, const int* in_sizes, int n_in,
                              void* d_out, int out_size, void* d_ws, size_t ws_size,
                              hipStream_t stream) {
    const float* x   = (const float*)d_in[0];
    const float* Wk  = (const float*)d_in[1];
    const float* Wq  = (const float*)d_in[2];
    const float* Wv  = (const float*)d_in[3];
    const float* Wp  = (const float*)d_in[4];
    const float* bp  = (const float*)d_in[5];
    const float* W1  = (const float*)d_in[6];
    const float* b1  = (const float*)d_in[7];
    const float* W2  = (const float*)d_in[8];
    const float* b2  = (const float*)d_in[9];
    const float* g1  = (const float*)d_in[10];
    const float* be1 = (const float*)d_in[11];
    const float* g2  = (const float*)d_in[12];
    const float* be2 = (const float*)d_in[13];
    float* out = (float*)d_out;

    char* ws = (char*)d_ws;
    bf16* Wqkv_t = (bf16*)(ws + 0);          //  6 MB [3072][1024]
    bf16* Wp_t   = (bf16*)(ws + 6291456);    //  2 MB [1024][1024]
    bf16* W1_t   = (bf16*)(ws + 8388608);    //  8 MB [4096][1024]
    bf16* W2_t   = (bf16*)(ws + 16777216);   //  8 MB [1024][4096]
    bf16* h      = (bf16*)(ws + 25165824);   //  8 MB [4096][1024] (reused as h2)
    bf16* qkv    = (bf16*)(ws + 33554432);   // 24 MB [4096][3072]
    bf16* Vt     = (bf16*)(ws + 58720256);   //  8 MB [B,H,HD,T]
    bf16* attnO  = (bf16*)(ws + 67108864);   //  8 MB [4096][1024]
    bf16* ff1    = (bf16*)(ws + 33554432);   // 32 MB, reuses qkv+Vt (dead after flash)
    float* x2    = (ws_size >= 92274688) ? (float*)(ws + 75497472) : out;  // 16 MB

    dim3 tb(32, 8);
    transpose_cvt<<<dim3(32, 32),  tb, 0, stream>>>(Wq, Wqkv_t,               1024, 1024);
    transpose_cvt<<<dim3(32, 32),  tb, 0, stream>>>(Wk, Wqkv_t + 1024*1024,   1024, 1024);
    transpose_cvt<<<dim3(32, 32),  tb, 0, stream>>>(Wv, Wqkv_t + 2048*1024,   1024, 1024);
    transpose_cvt<<<dim3(32, 32),  tb, 0, stream>>>(Wp, Wp_t,                 1024, 1024);
    transpose_cvt<<<dim3(128, 32), tb, 0, stream>>>(W1, W1_t,                 1024, 4096);
    transpose_cvt<<<dim3(32, 128), tb, 0, stream>>>(W2, W2_t,                 4096, 1024);

    ln_kernel<<<NT, 256, 0, stream>>>(x, g1, be1, h);
    gemm128<0><<<dim3(24, 32), 256, 0, stream>>>(h, Wqkv_t, qkv, nullptr, nullptr, NT, 3072, 1024);
    v_transpose<<<dim3(64, 2, 32), tb, 0, stream>>>(qkv, Vt);
    flash_attn<<<dim3(32, 32), 256, 0, stream>>>(qkv, Vt, attnO);
    gemm128<1><<<dim3(8, 32), 256, 0, stream>>>(attnO, Wp_t, x2, bp, x, NT, 1024, 1024);
    ln_kernel<<<NT, 256, 0, stream>>>(x2, g2, be2, h);
    gemm128<2><<<dim3(32, 32), 256, 0, stream>>>(h, W1_t, ff1, b1, nullptr, NT, 4096, 1024);
    gemm128<1><<<dim3(8, 32), 256, 0, stream>>>(ff1, W2_t, out, b2, x2, NT, 1024, 4096);
}

// Round 2
// 379.436 us; speedup vs baseline: 1.2891x; 1.2891x over previous
//
#include <hip/hip_runtime.h>
#include <hip/hip_bf16.h>

#define B_ 2
#define T_ 2048
#define E_ 1024
#define H_ 16
#define HD_ 64
#define NT (B_*T_)

typedef __attribute__((ext_vector_type(8))) short s16x8;
typedef __attribute__((ext_vector_type(4))) float f32x4;
typedef __attribute__((ext_vector_type(4))) unsigned int u32x4;

using bf16 = __hip_bfloat16;

#define MFMA16(a,b,c) __builtin_amdgcn_mfma_f32_16x16x32_bf16(a,b,c,0,0,0)

__device__ inline unsigned short f2bf(float f) {
    bf16 h = __float2bfloat16(f);
    return *reinterpret_cast<unsigned short*>(&h);
}

// async global->LDS, 16B per lane. lptr MUST be wave-uniform (HW: base + lane*16).
__device__ __forceinline__ void async_cp16(const void* g, void* l) {
    __builtin_amdgcn_global_load_lds((const __attribute__((address_space(1))) void*)g,
                                     (__attribute__((address_space(3))) void*)l,
                                     16, 0, 0);
}

// ---------------- weight transpose + fp32->bf16 ----------------
__global__ __launch_bounds__(256) void transpose_cvt(const float* __restrict__ W,
                                                     bf16* __restrict__ Wt,
                                                     int K, int N) {
    __shared__ float tile[32][33];
    int tx = threadIdx.x, ty = threadIdx.y;
    int n0 = blockIdx.x * 32, k0 = blockIdx.y * 32;
#pragma unroll
    for (int i = 0; i < 4; ++i)
        tile[ty + i*8][tx] = W[(size_t)(k0 + ty + i*8)*N + n0 + tx];
    __syncthreads();
#pragma unroll
    for (int i = 0; i < 4; ++i)
        Wt[(size_t)(n0 + ty + i*8)*K + k0 + tx] = __float2bfloat16(tile[tx][ty + i*8]);
}

// ---------------- LayerNorm (fp32 in -> bf16 out) ----------------
__global__ __launch_bounds__(256) void ln_kernel(const float* __restrict__ x,
                                                 const float* __restrict__ g,
                                                 const float* __restrict__ b,
                                                 bf16* __restrict__ h) {
    int row = blockIdx.x;
    int tid = threadIdx.x;
    const float4 xv = *reinterpret_cast<const float4*>(x + (size_t)row*E_ + tid*4);
    float s  = xv.x + xv.y + xv.z + xv.w;
    float sq = xv.x*xv.x + xv.y*xv.y + xv.z*xv.z + xv.w*xv.w;
#pragma unroll
    for (int o = 32; o > 0; o >>= 1) { s += __shfl_xor(s, o); sq += __shfl_xor(sq, o); }
    __shared__ float red[8];
    int w = tid >> 6, lane = tid & 63;
    if (lane == 0) { red[w] = s; red[4 + w] = sq; }
    __syncthreads();
    float S = red[0] + red[1] + red[2] + red[3];
    float Q = red[4] + red[5] + red[6] + red[7];
    float mu = S * (1.0f/E_);
    float var = Q * (1.0f/E_) - mu*mu;
    float rs = rsqrtf(var + 1e-5f);
    const float4 gv = *reinterpret_cast<const float4*>(g + tid*4);
    const float4 bv = *reinterpret_cast<const float4*>(b + tid*4);
    ushort4 o4;
    o4.x = f2bf((xv.x - mu)*rs*gv.x + bv.x);
    o4.y = f2bf((xv.y - mu)*rs*gv.y + bv.y);
    o4.z = f2bf((xv.z - mu)*rs*gv.z + bv.z);
    o4.w = f2bf((xv.w - mu)*rs*gv.w + bv.w);
    *reinterpret_cast<ushort4*>(h + (size_t)row*E_ + tid*4) = o4;
}

// ---------------- 128x128 bf16 MFMA GEMM (m97 structure) ----------------
// A [M][K] bf16, Bt [N][K] bf16. global_load_lds width-16 staging, linear LDS.
template<int EPI>
__global__ __launch_bounds__(256)
void gemm128(const bf16* __restrict__ A, const bf16* __restrict__ Bt, void* Cout,
             const float* __restrict__ bias, const float* res,
             int M, int N, int K) {
    __shared__ bf16 As[128*32];
    __shared__ bf16 Bs[128*32];
    int tid = threadIdx.x;
    int lane = tid & 63, w = tid >> 6;
    int wr = w >> 1, wc = w & 1;
    int m0 = blockIdx.y * 128, n0 = blockIdx.x * 128;
    int lr = lane & 15, lq = lane >> 4;
    f32x4 acc[4][4] = {};
    // staging geometry: issue i, wave w covers LDS bytes i*4096 + w*1024 + lane*16
    // -> row = i*64 + w*16 + (lane>>2), 16B chunk = lane&3
    int srow = w*16 + (lane >> 2);
    int soff = (lane & 3) * 8;
    const bf16* Ap = A  + (size_t)(m0 + srow)*K + soff;
    const bf16* Bp = Bt + (size_t)(n0 + srow)*K + soff;
    for (int k0 = 0; k0 < K; k0 += 32) {
#pragma unroll
        for (int i = 0; i < 2; ++i) {
            async_cp16(Ap + (size_t)(i*64)*K + k0, (char*)As + i*4096 + w*1024);
            async_cp16(Bp + (size_t)(i*64)*K + k0, (char*)Bs + i*4096 + w*1024);
        }
        __syncthreads();   // compiler emits vmcnt(0) drain + barrier (m97 structure)
        s16x8 af[4], bfr[4];
#pragma unroll
        for (int m = 0; m < 4; ++m)
            af[m] = *reinterpret_cast<const s16x8*>(As + (wr*64 + m*16 + lr)*32 + lq*8);
#pragma unroll
        for (int n = 0; n < 4; ++n)
            bfr[n] = *reinterpret_cast<const s16x8*>(Bs + (wc*64 + n*16 + lr)*32 + lq*8);
#pragma unroll
        for (int m = 0; m < 4; ++m)
#pragma unroll
            for (int n = 0; n < 4; ++n)
                acc[m][n] = MFMA16(af[m], bfr[n], acc[m][n]);
        __syncthreads();
    }
#pragma unroll
    for (int m = 0; m < 4; ++m) {
#pragma unroll
        for (int n = 0; n < 4; ++n) {
            int col = n0 + wc*64 + n*16 + lr;
#pragma unroll
            for (int r = 0; r < 4; ++r) {
                int row = m0 + wr*64 + m*16 + lq*4 + r;
                float v = acc[m][n][r];
                if (EPI == 0) {
                    reinterpret_cast<bf16*>(Cout)[(size_t)row*N + col] = __float2bfloat16(v);
                } else if (EPI == 1) {
                    reinterpret_cast<float*>(Cout)[(size_t)row*N + col] =
                        v + bias[col] + res[(size_t)row*N + col];
                } else {
                    v += bias[col];
                    v = v > 0.f ? v : 0.f;
                    reinterpret_cast<bf16*>(Cout)[(size_t)row*N + col] = __float2bfloat16(v);
                }
            }
        }
    }
}

// ---------------- V transpose: qkv v-section -> Vt [B,H,HD,T] ----------------
__global__ __launch_bounds__(256) void v_transpose(const bf16* __restrict__ qkv,
                                                   bf16* __restrict__ Vt) {
    __shared__ unsigned short tile[32][33];
    int tx = threadIdx.x, ty = threadIdx.y;
    int bh = blockIdx.z;
    int b = bh >> 4, h = bh & 15;
    int t0 = blockIdx.x * 32, d0 = blockIdx.y * 32;
    const unsigned short* src = reinterpret_cast<const unsigned short*>(qkv);
#pragma unroll
    for (int i = 0; i < 4; ++i)
        tile[ty + i*8][tx] = src[(size_t)(b*T_ + t0 + ty + i*8)*3072 + 2048 + h*64 + d0 + tx];
    __syncthreads();
    unsigned short* dst = reinterpret_cast<unsigned short*>(Vt);
#pragma unroll
    for (int i = 0; i < 4; ++i)
        dst[(size_t)(bh*64 + d0 + ty + i*8)*T_ + t0 + tx] = tile[tx][ty + i*8];
}

// ---------------- causal flash attention v2 ----------------
// grid (T/64, B*H), 256 threads (4 waves x 16 q-rows).
// K/V tiles double-buffered in LDS via global_load_lds (counted vmcnt, raw barriers).
// LDS layout: K tile [64 kv][8 chunks of 16B] with chunk ^= (row&7) swizzle, applied
// by pre-swizzling the GLOBAL source address (rule 21); same for V tile [64 d][64 kv].
__global__ __launch_bounds__(256)
void flash_attn(const bf16* __restrict__ qkv, const bf16* __restrict__ Vt,
                bf16* __restrict__ O) {
    __shared__ char smem[40960];   // K dbuf 16K | V dbuf 16K | P 4x2K
    int tid = threadIdx.x;
    int lane = tid & 63, w = tid >> 6;
    int lr = lane & 15, lq = lane >> 4;
    int bh = blockIdx.y, b = bh >> 4, h = bh & 15;
    int q0 = (int)(gridDim.x - 1 - blockIdx.x) * 64;   // heavy-first dispatch
    int qw = q0 + w * 16;
    const bf16* Qb = qkv + (size_t)(b*T_)*3072 + h*HD_;
    const bf16* Kb = Qb + 1024;
    const bf16* Vb = Vt + (size_t)bh * HD_ * T_;
    char* Pw = smem + 32768 + w*2048;

    // staging lane constants: dest row = i*32 + w*8 + (lane>>3), phys chunk = lane&7
    // logical source chunk = phys ^ (row&7) = (lane&7) ^ ((lane>>3)&7)
    int sc_   = (((lane & 7) ^ ((lane >> 3) & 7))) * 8;  // element offset in 64-elem row
    int srow_ = w*8 + (lane >> 3);

    s16x8 qf[2];
#pragma unroll
    for (int kk = 0; kk < 2; ++kk)
        qf[kk] = *reinterpret_cast<const s16x8*>(Qb + (size_t)(qw + lr)*3072 + kk*32 + lq*8);
    f32x4 od[4] = {};
    float mrun[4], lrun[4];
#pragma unroll
    for (int r = 0; r < 4; ++r) { mrun[r] = -1e30f; lrun[r] = 0.f; }
    const float SLOG2E = 0.125f * 1.44269504088896f;
    int ntiles = (q0 >> 6) + 1;

#define STAGE(bufi, tile) do {                                                          \
        int kv0s_ = (tile) * 64;                                                        \
        _Pragma("unroll")                                                               \
        for (int i_ = 0; i_ < 2; ++i_) {                                                \
            int rr_ = i_*32 + srow_;                                                    \
            async_cp16(Kb + (size_t)(kv0s_ + rr_)*3072 + sc_,                           \
                       smem + (bufi)*8192 + i_*4096 + w*1024);                          \
            async_cp16(Vb + (size_t)rr_*2048 + kv0s_ + sc_,                             \
                       smem + 16384 + (bufi)*8192 + i_*4096 + w*1024);                  \
        } } while (0)

    STAGE(0, 0);
    for (int it = 0; it < ntiles; ++it) {
        int curb = it & 1;
        int kv0 = it * 64;
        if (it + 1 < ntiles) {
            STAGE(curb ^ 1, it + 1);
            asm volatile("s_waitcnt vmcnt(4)" ::: "memory");   // cur tile landed, next in flight
        } else {
            asm volatile("s_waitcnt vmcnt(0)" ::: "memory");
        }
        __builtin_amdgcn_sched_barrier(0);
        __builtin_amdgcn_s_barrier();
        __builtin_amdgcn_sched_barrier(0);
        const char* Kt = smem + curb*8192;
        const char* Vtl = smem + 16384 + curb*8192;
        f32x4 sc[4];
#pragma unroll
        for (int n = 0; n < 4; ++n) {
            int row = n*16 + lr;
            s16x8 kf0 = *reinterpret_cast<const s16x8*>(Kt + row*128 + ((lq ^ (row&7)) << 4));
            s16x8 kf1 = *reinterpret_cast<const s16x8*>(Kt + row*128 + (((4+lq) ^ (row&7)) << 4));
            f32x4 z = {0.f, 0.f, 0.f, 0.f};
            z = MFMA16(qf[0], kf0, z);
            z = MFMA16(qf[1], kf1, z);
            sc[n] = z;
        }
        bool last = (it == ntiles - 1);
        float tmax[4] = {-1e30f, -1e30f, -1e30f, -1e30f};
#pragma unroll
        for (int n = 0; n < 4; ++n) {
#pragma unroll
            for (int r = 0; r < 4; ++r) {
                float v = sc[n][r] * SLOG2E;
                if (last) {
                    int row = qw + lq*4 + r;
                    int col = kv0 + n*16 + lr;
                    if (col > row) v = -1e30f;
                }
                sc[n][r] = v;
                tmax[r] = fmaxf(tmax[r], v);
            }
        }
#pragma unroll
        for (int r = 0; r < 4; ++r) {
#pragma unroll
            for (int o = 8; o > 0; o >>= 1)
                tmax[r] = fmaxf(tmax[r], __shfl_xor(tmax[r], o));
        }
        float corr[4], psum[4];
#pragma unroll
        for (int r = 0; r < 4; ++r) {
            float mn = fmaxf(mrun[r], tmax[r]);
            corr[r] = exp2f(mrun[r] - mn);
            mrun[r] = mn;
            psum[r] = 0.f;
        }
#pragma unroll
        for (int n = 0; n < 4; ++n) {
#pragma unroll
            for (int r = 0; r < 4; ++r) {
                float p = exp2f(sc[n][r] - mrun[r]);
                psum[r] += p;
                int rowl = lq*4 + r;
                int bo = (rowl*128 + (n*16 + lr)*2) ^ ((rowl & 7) << 4);  // XOR-swizzle (G4)
                *reinterpret_cast<unsigned short*>(Pw + bo) = f2bf(p);
            }
        }
#pragma unroll
        for (int r = 0; r < 4; ++r) {
#pragma unroll
            for (int o = 8; o > 0; o >>= 1)
                psum[r] += __shfl_xor(psum[r], o);
            lrun[r] = lrun[r]*corr[r] + psum[r];
        }
#pragma unroll
        for (int nd = 0; nd < 4; ++nd)
#pragma unroll
            for (int r = 0; r < 4; ++r)
                od[nd][r] *= corr[r];
        s16x8 pa[2];
#pragma unroll
        for (int kk = 0; kk < 2; ++kk) {
            int bo = (lr*128 + kk*64 + lq*16) ^ ((lr & 7) << 4);
            pa[kk] = *reinterpret_cast<const s16x8*>(Pw + bo);
        }
#pragma unroll
        for (int nd = 0; nd < 4; ++nd) {
            int row = nd*16 + lr;
            s16x8 vf0 = *reinterpret_cast<const s16x8*>(Vtl + row*128 + ((lq ^ (row&7)) << 4));
            s16x8 vf1 = *reinterpret_cast<const s16x8*>(Vtl + row*128 + (((4+lq) ^ (row&7)) << 4));
            od[nd] = MFMA16(pa[0], vf0, od[nd]);
            od[nd] = MFMA16(pa[1], vf1, od[nd]);
        }
        __builtin_amdgcn_sched_barrier(0);
        __builtin_amdgcn_s_barrier();   // reads done before next STAGE overwrites
        __builtin_amdgcn_sched_barrier(0);
    }
#undef STAGE
#pragma unroll
    for (int nd = 0; nd < 4; ++nd) {
#pragma unroll
        for (int r = 0; r < 4; ++r) {
            int row = qw + lq*4 + r;
            float v = od[nd][r] / lrun[r];
            O[(size_t)(b*T_ + row)*E_ + h*HD_ + nd*16 + lr] = __float2bfloat16(v);
        }
    }
}

// ---------------- launch ----------------
extern "C" void kernel_launch(void* const* d_in, const int* in_sizes, int n_in,
                              void* d_out, int out_size, void* d_ws, size_t ws_size,
                              hipStream_t stream) {
    const float* x   = (const float*)d_in[0];
    const float* Wk  = (const float*)d_in[1];
    const float* Wq  = (const float*)d_in[2];
    const float* Wv  = (const float*)d_in[3];
    const float* Wp  = (const float*)d_in[4];
    const float* bp  = (const float*)d_in[5];
    const float* W1  = (const float*)d_in[6];
    const float* b1  = (const float*)d_in[7];
    const float* W2  = (const float*)d_in[8];
    const float* b2  = (const float*)d_in[9];
    const float* g1  = (const float*)d_in[10];
    const float* be1 = (const float*)d_in[11];
    const float* g2  = (const float*)d_in[12];
    const float* be2 = (const float*)d_in[13];
    float* out = (float*)d_out;

    char* ws = (char*)d_ws;
    bf16* Wqkv_t = (bf16*)(ws + 0);          //  6 MB [3072][1024]
    bf16* Wp_t   = (bf16*)(ws + 6291456);    //  2 MB [1024][1024]
    bf16* W1_t   = (bf16*)(ws + 8388608);    //  8 MB [4096][1024]
    bf16* W2_t   = (bf16*)(ws + 16777216);   //  8 MB [1024][4096]
    bf16* h      = (bf16*)(ws + 25165824);   //  8 MB [4096][1024] (reused as h2)
    bf16* qkv    = (bf16*)(ws + 33554432);   // 24 MB [4096][3072]
    bf16* Vt     = (bf16*)(ws + 58720256);   //  8 MB [B,H,HD,T]
    bf16* attnO  = (bf16*)(ws + 67108864);   //  8 MB [4096][1024]
    bf16* ff1    = (bf16*)(ws + 33554432);   // 32 MB, reuses qkv+Vt (dead after flash)
    float* x2    = (ws_size >= 92274688) ? (float*)(ws + 75497472) : out;  // 16 MB

    dim3 tb(32, 8);
    transpose_cvt<<<dim3(32, 32),  tb, 0, stream>>>(Wq, Wqkv_t,               1024, 1024);
    transpose_cvt<<<dim3(32, 32),  tb, 0, stream>>>(Wk, Wqkv_t + 1024*1024,   1024, 1024);
    transpose_cvt<<<dim3(32, 32),  tb, 0, stream>>>(Wv, Wqkv_t + 2048*1024,   1024, 1024);
    transpose_cvt<<<dim3(32, 32),  tb, 0, stream>>>(Wp, Wp_t,                 1024, 1024);
    transpose_cvt<<<dim3(128, 32), tb, 0, stream>>>(W1, W1_t,                 1024, 4096);
    transpose_cvt<<<dim3(32, 128), tb, 0, stream>>>(W2, W2_t,                 4096, 1024);

    ln_kernel<<<NT, 256, 0, stream>>>(x, g1, be1, h);
    gemm128<0><<<dim3(24, 32), 256, 0, stream>>>(h, Wqkv_t, qkv, nullptr, nullptr, NT, 3072, 1024);
    v_transpose<<<dim3(64, 2, 32), tb, 0, stream>>>(qkv, Vt);
    flash_attn<<<dim3(32, 32), 256, 0, stream>>>(qkv, Vt, attnO);
    gemm128<1><<<dim3(8, 32), 256, 0, stream>>>(attnO, Wp_t, x2, bp, x, NT, 1024, 1024);
    ln_kernel<<<NT, 256, 0, stream>>>(x2, g2, be2, h);
    gemm128<2><<<dim3(32, 32), 256, 0, stream>>>(h, W1_t, ff1, b1, nullptr, NT, 4096, 1024);
    gemm128<1><<<dim3(8, 32), 256, 0, stream>>>(ff1, W2_t, out, b2, x2, NT, 1024, 4096);
}

// Round 3
// 318.617 us; speedup vs baseline: 1.5352x; 1.1909x over previous
//
#include <hip/hip_runtime.h>
#include <hip/hip_bf16.h>

#define B_ 2
#define T_ 2048
#define E_ 1024
#define H_ 16
#define HD_ 64
#define NT (B_*T_)

typedef __attribute__((ext_vector_type(8))) short s16x8;
typedef __attribute__((ext_vector_type(4))) float f32x4;
typedef __attribute__((ext_vector_type(4))) unsigned int u32x4;

using bf16 = __hip_bfloat16;

#define MFMA16(a,b,c) __builtin_amdgcn_mfma_f32_16x16x32_bf16(a,b,c,0,0,0)

__device__ inline unsigned short f2bf(float f) {
    bf16 h = __float2bfloat16(f);
    return *reinterpret_cast<unsigned short*>(&h);
}

// async global->LDS, 16B per lane. LDS dest is wave-uniform base + lane*16.
__device__ __forceinline__ void async_cp16(const void* g, void* l) {
    __builtin_amdgcn_global_load_lds((const __attribute__((address_space(1))) void*)g,
                                     (__attribute__((address_space(3))) void*)l,
                                     16, 0, 0);
}

// ---------------- 4x weight transpose + fp32->bf16 (1024x1024 each) ----------------
__global__ __launch_bounds__(256) void transpose_cvt4(const float* __restrict__ W0,
                                                      const float* __restrict__ W1,
                                                      const float* __restrict__ W2,
                                                      const float* __restrict__ W3,
                                                      bf16* __restrict__ Wt) {
    __shared__ float tile[32][33];
    int tx = threadIdx.x, ty = threadIdx.y;
    int z = blockIdx.z;
    const float* W = z == 0 ? W0 : z == 1 ? W1 : z == 2 ? W2 : W3;
    bf16* dst = Wt + (size_t)z * 1024 * 1024;
    int n0 = blockIdx.x * 32, k0 = blockIdx.y * 32;
#pragma unroll
    for (int i = 0; i < 4; ++i)
        tile[ty + i*8][tx] = W[(size_t)(k0 + ty + i*8)*1024 + n0 + tx];
    __syncthreads();
#pragma unroll
    for (int i = 0; i < 4; ++i)
        dst[(size_t)(n0 + ty + i*8)*1024 + k0 + tx] = __float2bfloat16(tile[tx][ty + i*8]);
}

// generic K x N transpose (for W1, W2)
__global__ __launch_bounds__(256) void transpose_cvt(const float* __restrict__ W,
                                                     bf16* __restrict__ Wt,
                                                     int K, int N) {
    __shared__ float tile[32][33];
    int tx = threadIdx.x, ty = threadIdx.y;
    int n0 = blockIdx.x * 32, k0 = blockIdx.y * 32;
#pragma unroll
    for (int i = 0; i < 4; ++i)
        tile[ty + i*8][tx] = W[(size_t)(k0 + ty + i*8)*N + n0 + tx];
    __syncthreads();
#pragma unroll
    for (int i = 0; i < 4; ++i)
        Wt[(size_t)(n0 + ty + i*8)*K + k0 + tx] = __float2bfloat16(tile[tx][ty + i*8]);
}

// ---------------- LayerNorm (fp32 in -> bf16 out) ----------------
__global__ __launch_bounds__(256) void ln_kernel(const float* __restrict__ x,
                                                 const float* __restrict__ g,
                                                 const float* __restrict__ b,
                                                 bf16* __restrict__ h) {
    int row = blockIdx.x;
    int tid = threadIdx.x;
    const float4 xv = *reinterpret_cast<const float4*>(x + (size_t)row*E_ + tid*4);
    float s  = xv.x + xv.y + xv.z + xv.w;
    float sq = xv.x*xv.x + xv.y*xv.y + xv.z*xv.z + xv.w*xv.w;
#pragma unroll
    for (int o = 32; o > 0; o >>= 1) { s += __shfl_xor(s, o); sq += __shfl_xor(sq, o); }
    __shared__ float red[8];
    int w = tid >> 6, lane = tid & 63;
    if (lane == 0) { red[w] = s; red[4 + w] = sq; }
    __syncthreads();
    float S = red[0] + red[1] + red[2] + red[3];
    float Q = red[4] + red[5] + red[6] + red[7];
    float mu = S * (1.0f/E_);
    float var = Q * (1.0f/E_) - mu*mu;
    float rs = rsqrtf(var + 1e-5f);
    const float4 gv = *reinterpret_cast<const float4*>(g + tid*4);
    const float4 bv = *reinterpret_cast<const float4*>(b + tid*4);
    ushort4 o4;
    o4.x = f2bf((xv.x - mu)*rs*gv.x + bv.x);
    o4.y = f2bf((xv.y - mu)*rs*gv.y + bv.y);
    o4.z = f2bf((xv.z - mu)*rs*gv.z + bv.z);
    o4.w = f2bf((xv.w - mu)*rs*gv.w + bv.w);
    *reinterpret_cast<ushort4*>(h + (size_t)row*E_ + tid*4) = o4;
}

// ---------------- 128xBN bf16 MFMA GEMM (m97 structure) ----------------
// A [M][K] bf16, Bt [N][K] bf16. BN = 128 (big N) or 64 (N=1024 grids -> 2 blocks/CU).
// EPI: 0 = bf16 out; 1 = f32 out + bias + res; 2 = relu(acc+bias) bf16
template<int BN, int EPI>
__global__ __launch_bounds__(256)
void gemm_t(const bf16* __restrict__ A, const bf16* __restrict__ Bt, void* Cout,
            const float* __restrict__ bias, const float* res,
            int M, int N, int K) {
    constexpr int NB = BN / 32;     // MFMA col-tiles per wave
    constexpr int HALF = BN / 2;    // per-wave-col span
    __shared__ bf16 As[128*32];
    __shared__ bf16 Bs[BN*32];
    int tid = threadIdx.x;
    int lane = tid & 63, w = tid >> 6;
    int wr = w >> 1, wc = w & 1;
    int m0 = blockIdx.y * 128, n0 = blockIdx.x * BN;
    int lr = lane & 15, lq = lane >> 4;
    f32x4 acc[4][NB] = {};
    // staging: issue i, wave w covers LDS bytes i*4096 + w*1024 + lane*16
    // -> row = i*64 + w*16 + (lane>>2), 16B chunk = lane&3
    int srow = w*16 + (lane >> 2);
    int soff = (lane & 3) * 8;
    const bf16* Ap = A  + (size_t)(m0 + srow)*K + soff;
    const bf16* Bp = Bt + (size_t)(n0 + srow)*K + soff;
    for (int k0 = 0; k0 < K; k0 += 32) {
#pragma unroll
        for (int i = 0; i < 2; ++i)
            async_cp16(Ap + (size_t)(i*64)*K + k0, (char*)As + i*4096 + w*1024);
#pragma unroll
        for (int i = 0; i < BN/64; ++i)
            async_cp16(Bp + (size_t)(i*64)*K + k0, (char*)Bs + i*4096 + w*1024);
        __syncthreads();
        s16x8 af[4], bfr[NB];
#pragma unroll
        for (int m = 0; m < 4; ++m)
            af[m] = *reinterpret_cast<const s16x8*>(As + (wr*64 + m*16 + lr)*32 + lq*8);
#pragma unroll
        for (int n = 0; n < NB; ++n)
            bfr[n] = *reinterpret_cast<const s16x8*>(Bs + (wc*HALF + n*16 + lr)*32 + lq*8);
        __builtin_amdgcn_s_setprio(1);
#pragma unroll
        for (int m = 0; m < 4; ++m)
#pragma unroll
            for (int n = 0; n < NB; ++n)
                acc[m][n] = MFMA16(af[m], bfr[n], acc[m][n]);
        __builtin_amdgcn_s_setprio(0);
        __syncthreads();
    }
#pragma unroll
    for (int m = 0; m < 4; ++m) {
#pragma unroll
        for (int n = 0; n < NB; ++n) {
            int col = n0 + wc*HALF + n*16 + lr;
#pragma unroll
            for (int r = 0; r < 4; ++r) {
                int row = m0 + wr*64 + m*16 + lq*4 + r;
                float v = acc[m][n][r];
                if (EPI == 0) {
                    reinterpret_cast<bf16*>(Cout)[(size_t)row*N + col] = __float2bfloat16(v);
                } else if (EPI == 1) {
                    reinterpret_cast<float*>(Cout)[(size_t)row*N + col] =
                        v + bias[col] + res[(size_t)row*N + col];
                } else {
                    v += bias[col];
                    v = v > 0.f ? v : 0.f;
                    reinterpret_cast<bf16*>(Cout)[(size_t)row*N + col] = __float2bfloat16(v);
                }
            }
        }
    }
}

// ---------------- V transpose: qkv v-section -> Vt [B,H,HD,T] ----------------
__global__ __launch_bounds__(256) void v_transpose(const bf16* __restrict__ qkv,
                                                   bf16* __restrict__ Vt) {
    __shared__ unsigned short tile[32][33];
    int tx = threadIdx.x, ty = threadIdx.y;
    int bh = blockIdx.z;
    int b = bh >> 4, h = bh & 15;
    int t0 = blockIdx.x * 32, d0 = blockIdx.y * 32;
    const unsigned short* src = reinterpret_cast<const unsigned short*>(qkv);
#pragma unroll
    for (int i = 0; i < 4; ++i)
        tile[ty + i*8][tx] = src[(size_t)(b*T_ + t0 + ty + i*8)*3072 + 2048 + h*64 + d0 + tx];
    __syncthreads();
    unsigned short* dst = reinterpret_cast<unsigned short*>(Vt);
#pragma unroll
    for (int i = 0; i < 4; ++i)
        dst[(size_t)(bh*64 + d0 + ty + i*8)*T_ + t0 + tx] = tile[tx][ty + i*8];
}

// ---------------- causal flash attention v3 ----------------
// grid (32, B*H), 256 threads (4 waves x 16 q-rows).
// qt swizzled (x+y)&31 so each CU's resident blocks span causal depths (load balance).
__global__ __launch_bounds__(256)
void flash_attn(const bf16* __restrict__ qkv, const bf16* __restrict__ Vt,
                bf16* __restrict__ O) {
    __shared__ char smem[40960];   // K dbuf 16K | V dbuf 16K | P 4x2K
    int tid = threadIdx.x;
    int lane = tid & 63, w = tid >> 6;
    int lr = lane & 15, lq = lane >> 4;
    int bh = blockIdx.y, b = bh >> 4, h = bh & 15;
    int qt = (int)((blockIdx.x + blockIdx.y) & 31);   // balance causal depth across CUs
    int q0 = qt * 64;
    int qw = q0 + w * 16;
    const bf16* Qb = qkv + (size_t)(b*T_)*3072 + h*HD_;
    const bf16* Kb = Qb + 1024;
    const bf16* Vb = Vt + (size_t)bh * HD_ * T_;
    char* Pw = smem + 32768 + w*2048;

    // staging: dest row = i*32 + w*8 + (lane>>3), phys chunk = lane&7,
    // logical source chunk = phys ^ (row&7)   (pre-swizzled source, rule 21)
    int sc_   = (((lane & 7) ^ ((lane >> 3) & 7))) * 8;
    int srow_ = w*8 + (lane >> 3);

    s16x8 qf[2];
#pragma unroll
    for (int kk = 0; kk < 2; ++kk)
        qf[kk] = *reinterpret_cast<const s16x8*>(Qb + (size_t)(qw + lr)*3072 + kk*32 + lq*8);
    f32x4 od[4] = {};
    float mrun[4], lrun[4];
#pragma unroll
    for (int r = 0; r < 4; ++r) { mrun[r] = -1e30f; lrun[r] = 0.f; }
    const float SLOG2E = 0.125f * 1.44269504088896f;
    int ntiles = qt + 1;

#define STAGE(bufi, tile) do {                                                          \
        int kv0s_ = (tile) * 64;                                                        \
        _Pragma("unroll")                                                               \
        for (int i_ = 0; i_ < 2; ++i_) {                                                \
            int rr_ = i_*32 + srow_;                                                    \
            async_cp16(Kb + (size_t)(kv0s_ + rr_)*3072 + sc_,                           \
                       smem + (bufi)*8192 + i_*4096 + w*1024);                          \
            async_cp16(Vb + (size_t)rr_*2048 + kv0s_ + sc_,                             \
                       smem + 16384 + (bufi)*8192 + i_*4096 + w*1024);                  \
        } } while (0)

    STAGE(0, 0);
    for (int it = 0; it < ntiles; ++it) {
        int curb = it & 1;
        int kv0 = it * 64;
        if (it + 1 < ntiles) {
            STAGE(curb ^ 1, it + 1);
            asm volatile("s_waitcnt vmcnt(4)" ::: "memory");   // cur tile landed, next in flight
        } else {
            asm volatile("s_waitcnt vmcnt(0)" ::: "memory");
        }
        __builtin_amdgcn_sched_barrier(0);
        __builtin_amdgcn_s_barrier();
        __builtin_amdgcn_sched_barrier(0);
        const char* Kt = smem + curb*8192;
        const char* Vtl = smem + 16384 + curb*8192;
        f32x4 sc[4];
        __builtin_amdgcn_s_setprio(1);
#pragma unroll
        for (int n = 0; n < 4; ++n) {
            int row = n*16 + lr;
            s16x8 kf0 = *reinterpret_cast<const s16x8*>(Kt + row*128 + ((lq ^ (row&7)) << 4));
            s16x8 kf1 = *reinterpret_cast<const s16x8*>(Kt + row*128 + (((4+lq) ^ (row&7)) << 4));
            f32x4 z = {0.f, 0.f, 0.f, 0.f};
            z = MFMA16(qf[0], kf0, z);
            z = MFMA16(qf[1], kf1, z);
            sc[n] = z;
        }
        __builtin_amdgcn_s_setprio(0);
#pragma unroll
        for (int n = 0; n < 4; ++n)
#pragma unroll
            for (int r = 0; r < 4; ++r)
                sc[n][r] *= SLOG2E;
        if (it == ntiles - 1) {   // causal mask, once per block
#pragma unroll
            for (int n = 0; n < 4; ++n) {
#pragma unroll
                for (int r = 0; r < 4; ++r) {
                    int row = qw + lq*4 + r;
                    int col = kv0 + n*16 + lr;
                    if (col > row) sc[n][r] = -1e30f;
                }
            }
        }
        float tmax[4] = {-1e30f, -1e30f, -1e30f, -1e30f};
#pragma unroll
        for (int n = 0; n < 4; ++n)
#pragma unroll
            for (int r = 0; r < 4; ++r)
                tmax[r] = fmaxf(tmax[r], sc[n][r]);
#pragma unroll
        for (int r = 0; r < 4; ++r) {
#pragma unroll
            for (int o = 8; o > 0; o >>= 1)
                tmax[r] = fmaxf(tmax[r], __shfl_xor(tmax[r], o));
        }
        float corr[4], psum[4];
#pragma unroll
        for (int r = 0; r < 4; ++r) {
            float mn = fmaxf(mrun[r], tmax[r]);
            corr[r] = exp2f(mrun[r] - mn);
            mrun[r] = mn;
            psum[r] = 0.f;
        }
#pragma unroll
        for (int n = 0; n < 4; ++n) {
#pragma unroll
            for (int r = 0; r < 4; ++r) {
                float p = exp2f(sc[n][r] - mrun[r]);
                psum[r] += p;
                int rowl = lq*4 + r;
                int bo = (rowl*128 + (n*16 + lr)*2) ^ ((rowl & 7) << 4);  // XOR-swizzle (G4)
                *reinterpret_cast<unsigned short*>(Pw + bo) = f2bf(p);
            }
        }
#pragma unroll
        for (int r = 0; r < 4; ++r) {
#pragma unroll
            for (int o = 8; o > 0; o >>= 1)
                psum[r] += __shfl_xor(psum[r], o);
            lrun[r] = lrun[r]*corr[r] + psum[r];
        }
#pragma unroll
        for (int nd = 0; nd < 4; ++nd)
#pragma unroll
            for (int r = 0; r < 4; ++r)
                od[nd][r] *= corr[r];
        s16x8 pa[2];
#pragma unroll
        for (int kk = 0; kk < 2; ++kk) {
            int bo = (lr*128 + kk*64 + lq*16) ^ ((lr & 7) << 4);
            pa[kk] = *reinterpret_cast<const s16x8*>(Pw + bo);
        }
        __builtin_amdgcn_s_setprio(1);
#pragma unroll
        for (int nd = 0; nd < 4; ++nd) {
            int row = nd*16 + lr;
            s16x8 vf0 = *reinterpret_cast<const s16x8*>(Vtl + row*128 + ((lq ^ (row&7)) << 4));
            s16x8 vf1 = *reinterpret_cast<const s16x8*>(Vtl + row*128 + (((4+lq) ^ (row&7)) << 4));
            od[nd] = MFMA16(pa[0], vf0, od[nd]);
            od[nd] = MFMA16(pa[1], vf1, od[nd]);
        }
        __builtin_amdgcn_s_setprio(0);
        __builtin_amdgcn_sched_barrier(0);
        __builtin_amdgcn_s_barrier();   // reads done before next STAGE overwrites
        __builtin_amdgcn_sched_barrier(0);
    }
#undef STAGE
#pragma unroll
    for (int nd = 0; nd < 4; ++nd) {
#pragma unroll
        for (int r = 0; r < 4; ++r) {
            int row = qw + lq*4 + r;
            float v = od[nd][r] / lrun[r];
            O[(size_t)(b*T_ + row)*E_ + h*HD_ + nd*16 + lr] = __float2bfloat16(v);
        }
    }
}

// ---------------- launch ----------------
extern "C" void kernel_launch(void* const* d_in, const int* in_sizes, int n_in,
                              void* d_out, int out_size, void* d_ws, size_t ws_size,
                              hipStream_t stream) {
    const float* x   = (const float*)d_in[0];
    const float* Wk  = (const float*)d_in[1];
    const float* Wq  = (const float*)d_in[2];
    const float* Wv  = (const float*)d_in[3];
    const float* Wp  = (const float*)d_in[4];
    const float* bp  = (const float*)d_in[5];
    const float* W1  = (const float*)d_in[6];
    const float* b1  = (const float*)d_in[7];
    const float* W2  = (const float*)d_in[8];
    const float* b2  = (const float*)d_in[9];
    const float* g1  = (const float*)d_in[10];
    const float* be1 = (const float*)d_in[11];
    const float* g2  = (const float*)d_in[12];
    const float* be2 = (const float*)d_in[13];
    float* out = (float*)d_out;

    char* ws = (char*)d_ws;
    bf16* Wqkv_t = (bf16*)(ws + 0);          //  6 MB [3072][1024], then Wp_t right after
    bf16* Wp_t   = (bf16*)(ws + 6291456);    //  2 MB [1024][1024]
    bf16* W1_t   = (bf16*)(ws + 8388608);    //  8 MB [4096][1024]
    bf16* W2_t   = (bf16*)(ws + 16777216);   //  8 MB [1024][4096]
    bf16* h      = (bf16*)(ws + 25165824);   //  8 MB [4096][1024] (reused as h2)
    bf16* qkv    = (bf16*)(ws + 33554432);   // 24 MB [4096][3072]
    bf16* Vt     = (bf16*)(ws + 58720256);   //  8 MB [B,H,HD,T]
    bf16* attnO  = (bf16*)(ws + 67108864);   //  8 MB [4096][1024]
    bf16* ff1    = (bf16*)(ws + 33554432);   // 32 MB, reuses qkv+Vt (dead after flash)
    float* x2    = (ws_size >= 92274688) ? (float*)(ws + 75497472) : out;  // 16 MB

    dim3 tb(32, 8);
    transpose_cvt4<<<dim3(32, 32, 4), tb, 0, stream>>>(Wq, Wk, Wv, Wp, Wqkv_t);
    transpose_cvt<<<dim3(128, 32), tb, 0, stream>>>(W1, W1_t, 1024, 4096);
    transpose_cvt<<<dim3(32, 128), tb, 0, stream>>>(W2, W2_t, 4096, 1024);

    ln_kernel<<<NT, 256, 0, stream>>>(x, g1, be1, h);
    gemm_t<128,0><<<dim3(24, 32), 256, 0, stream>>>(h, Wqkv_t, qkv, nullptr, nullptr, NT, 3072, 1024);
    v_transpose<<<dim3(64, 2, 32), tb, 0, stream>>>(qkv, Vt);
    flash_attn<<<dim3(32, 32), 256, 0, stream>>>(qkv, Vt, attnO);
    gemm_t<64,1><<<dim3(16, 32), 256, 0, stream>>>(attnO, Wp_t, x2, bp, x, NT, 1024, 1024);
    ln_kernel<<<NT, 256, 0, stream>>>(x2, g2, be2, h);
    gemm_t<128,2><<<dim3(32, 32), 256, 0, stream>>>(h, W1_t, ff1, b1, nullptr, NT, 4096, 1024);
    gemm_t<64,1><<<dim3(16, 32), 256, 0, stream>>>(ff1, W2_t, out, b2, x2, NT, 1024, 4096);
}

// Round 4
// 240.207 us; speedup vs baseline: 2.0363x; 1.3264x over previous
//
#include <hip/hip_runtime.h>
#include <hip/hip_bf16.h>

#define B_ 2
#define T_ 2048
#define E_ 1024
#define H_ 16
#define HD_ 64
#define NT (B_*T_)

typedef __attribute__((ext_vector_type(8))) short s16x8;
typedef __attribute__((ext_vector_type(4))) float f32x4;
typedef __attribute__((ext_vector_type(4))) unsigned int u32x4;

using bf16 = __hip_bfloat16;

#define MFMA16(a,b,c) __builtin_amdgcn_mfma_f32_16x16x32_bf16(a,b,c,0,0,0)

__device__ inline unsigned short f2bf(float f) {
    bf16 h = __float2bfloat16(f);
    return *reinterpret_cast<unsigned short*>(&h);
}

// async global->LDS, 16B per lane. LDS dest is wave-uniform base + lane*16.
__device__ __forceinline__ void async_cp16(const void* g, void* l) {
    __builtin_amdgcn_global_load_lds((const __attribute__((address_space(1))) void*)g,
                                     (__attribute__((address_space(3))) void*)l,
                                     16, 0, 0);
}

// ---------------- 4x weight transpose + fp32->bf16 (1024x1024 each) ----------------
__global__ __launch_bounds__(256) void transpose_cvt4(const float* __restrict__ W0,
                                                      const float* __restrict__ W1,
                                                      const float* __restrict__ W2,
                                                      const float* __restrict__ W3,
                                                      bf16* __restrict__ Wt) {
    __shared__ float tile[32][33];
    int tx = threadIdx.x, ty = threadIdx.y;
    int z = blockIdx.z;
    const float* W = z == 0 ? W0 : z == 1 ? W1 : z == 2 ? W2 : W3;
    bf16* dst = Wt + (size_t)z * 1024 * 1024;
    int n0 = blockIdx.x * 32, k0 = blockIdx.y * 32;
#pragma unroll
    for (int i = 0; i < 4; ++i)
        tile[ty + i*8][tx] = W[(size_t)(k0 + ty + i*8)*1024 + n0 + tx];
    __syncthreads();
#pragma unroll
    for (int i = 0; i < 4; ++i)
        dst[(size_t)(n0 + ty + i*8)*1024 + k0 + tx] = __float2bfloat16(tile[tx][ty + i*8]);
}

// generic K x N transpose (for W1, W2)
__global__ __launch_bounds__(256) void transpose_cvt(const float* __restrict__ W,
                                                     bf16* __restrict__ Wt,
                                                     int K, int N) {
    __shared__ float tile[32][33];
    int tx = threadIdx.x, ty = threadIdx.y;
    int n0 = blockIdx.x * 32, k0 = blockIdx.y * 32;
#pragma unroll
    for (int i = 0; i < 4; ++i)
        tile[ty + i*8][tx] = W[(size_t)(k0 + ty + i*8)*N + n0 + tx];
    __syncthreads();
#pragma unroll
    for (int i = 0; i < 4; ++i)
        Wt[(size_t)(n0 + ty + i*8)*K + k0 + tx] = __float2bfloat16(tile[tx][ty + i*8]);
}

// ---------------- LayerNorm (fp32 in -> bf16 out) ----------------
__global__ __launch_bounds__(256) void ln_kernel(const float* __restrict__ x,
                                                 const float* __restrict__ g,
                                                 const float* __restrict__ b,
                                                 bf16* __restrict__ h) {
    int row = blockIdx.x;
    int tid = threadIdx.x;
    const float4 xv = *reinterpret_cast<const float4*>(x + (size_t)row*E_ + tid*4);
    float s  = xv.x + xv.y + xv.z + xv.w;
    float sq = xv.x*xv.x + xv.y*xv.y + xv.z*xv.z + xv.w*xv.w;
#pragma unroll
    for (int o = 32; o > 0; o >>= 1) { s += __shfl_xor(s, o); sq += __shfl_xor(sq, o); }
    __shared__ float red[8];
    int w = tid >> 6, lane = tid & 63;
    if (lane == 0) { red[w] = s; red[4 + w] = sq; }
    __syncthreads();
    float S = red[0] + red[1] + red[2] + red[3];
    float Q = red[4] + red[5] + red[6] + red[7];
    float mu = S * (1.0f/E_);
    float var = Q * (1.0f/E_) - mu*mu;
    float rs = rsqrtf(var + 1e-5f);
    const float4 gv = *reinterpret_cast<const float4*>(g + tid*4);
    const float4 bv = *reinterpret_cast<const float4*>(b + tid*4);
    ushort4 o4;
    o4.x = f2bf((xv.x - mu)*rs*gv.x + bv.x);
    o4.y = f2bf((xv.y - mu)*rs*gv.y + bv.y);
    o4.z = f2bf((xv.z - mu)*rs*gv.z + bv.z);
    o4.w = f2bf((xv.w - mu)*rs*gv.w + bv.w);
    *reinterpret_cast<ushort4*>(h + (size_t)row*E_ + tid*4) = o4;
}

// ---------------- 128xBN bf16 MFMA GEMM, BK=64, XOR-swizzled LDS ----------------
// A [M][K] bf16, Bt [N][K] bf16. EPI: 0 bf16; 1 f32+bias+res; 2 relu(acc+bias) bf16.
// LDS tiles [rows][64] bf16, 128B row stride; 16B chunk index ^= (row&7); the
// global source address is pre-swizzled so global_load_lds's linear dest lands right.
template<int BN, int EPI>
__global__ __launch_bounds__(256)
void gemm_t(const bf16* __restrict__ A, const bf16* __restrict__ Bt, void* Cout,
            const float* __restrict__ bias, const float* res,
            int M, int N, int K) {
    constexpr int NB = BN / 32;     // MFMA col-tiles per wave
    constexpr int HALF = BN / 2;    // per-wave-col span
    __shared__ bf16 As[128*64];
    __shared__ bf16 Bs[BN*64];
    int tid = threadIdx.x;
    int lane = tid & 63, w = tid >> 6;
    int wr = w >> 1, wc = w & 1;
    int m0 = blockIdx.y * 128, n0 = blockIdx.x * BN;
    int lr = lane & 15, lq = lane >> 4;
    f32x4 acc[4][NB] = {};
    // staging: issue i covers rows i*32 + w*8 + (lane>>3); phys 16B chunk = lane&7;
    // logical source chunk = phys ^ (row&7)
    int srow = w*8 + (lane >> 3);
    int schunk = ((lane & 7) ^ (srow & 7)) * 8;   // element offset in 64-elem row
    const bf16* Ap = A  + (size_t)(m0 + srow)*K + schunk;
    const bf16* Bp = Bt + (size_t)(n0 + srow)*K + schunk;
    for (int k0 = 0; k0 < K; k0 += 64) {
#pragma unroll
        for (int i = 0; i < 4; ++i)
            async_cp16(Ap + (size_t)(i*32)*K + k0, (char*)As + i*4096 + w*1024);
#pragma unroll
        for (int i = 0; i < BN/32; ++i)
            async_cp16(Bp + (size_t)(i*32)*K + k0, (char*)Bs + i*4096 + w*1024);
        __syncthreads();
        const char* Asb = (const char*)As;
        const char* Bsb = (const char*)Bs;
        s16x8 af[2][4], bfr[2][NB];
#pragma unroll
        for (int m = 0; m < 4; ++m) {
            int row = wr*64 + m*16 + lr;
            int base = row*128, sw = (row & 7) << 4;
#pragma unroll
            for (int kk = 0; kk < 2; ++kk)
                af[kk][m] = *reinterpret_cast<const s16x8*>(Asb + base + ((kk*64 + lq*16) ^ sw));
        }
#pragma unroll
        for (int n = 0; n < NB; ++n) {
            int row = wc*HALF + n*16 + lr;
            int base = row*128, sw = (row & 7) << 4;
#pragma unroll
            for (int kk = 0; kk < 2; ++kk)
                bfr[kk][n] = *reinterpret_cast<const s16x8*>(Bsb + base + ((kk*64 + lq*16) ^ sw));
        }
        __builtin_amdgcn_s_setprio(1);
#pragma unroll
        for (int kk = 0; kk < 2; ++kk)
#pragma unroll
            for (int m = 0; m < 4; ++m)
#pragma unroll
                for (int n = 0; n < NB; ++n)
                    acc[m][n] = MFMA16(af[kk][m], bfr[kk][n], acc[m][n]);
        __builtin_amdgcn_s_setprio(0);
        __syncthreads();
    }
#pragma unroll
    for (int m = 0; m < 4; ++m) {
#pragma unroll
        for (int n = 0; n < NB; ++n) {
            int col = n0 + wc*HALF + n*16 + lr;
#pragma unroll
            for (int r = 0; r < 4; ++r) {
                int row = m0 + wr*64 + m*16 + lq*4 + r;
                float v = acc[m][n][r];
                if (EPI == 0) {
                    reinterpret_cast<bf16*>(Cout)[(size_t)row*N + col] = __float2bfloat16(v);
                } else if (EPI == 1) {
                    reinterpret_cast<float*>(Cout)[(size_t)row*N + col] =
                        v + bias[col] + res[(size_t)row*N + col];
                } else {
                    v += bias[col];
                    v = v > 0.f ? v : 0.f;
                    reinterpret_cast<bf16*>(Cout)[(size_t)row*N + col] = __float2bfloat16(v);
                }
            }
        }
    }
}

// ---------------- V transpose: qkv v-section -> Vt [B,H,HD,T] ----------------
__global__ __launch_bounds__(256) void v_transpose(const bf16* __restrict__ qkv,
                                                   bf16* __restrict__ Vt) {
    __shared__ unsigned short tile[32][33];
    int tx = threadIdx.x, ty = threadIdx.y;
    int bh = blockIdx.z;
    int b = bh >> 4, h = bh & 15;
    int t0 = blockIdx.x * 32, d0 = blockIdx.y * 32;
    const unsigned short* src = reinterpret_cast<const unsigned short*>(qkv);
#pragma unroll
    for (int i = 0; i < 4; ++i)
        tile[ty + i*8][tx] = src[(size_t)(b*T_ + t0 + ty + i*8)*3072 + 2048 + h*64 + d0 + tx];
    __syncthreads();
    unsigned short* dst = reinterpret_cast<unsigned short*>(Vt);
#pragma unroll
    for (int i = 0; i < 4; ++i)
        dst[(size_t)(bh*64 + d0 + ty + i*8)*T_ + t0 + tx] = tile[tx][ty + i*8];
}

// ---------------- causal flash attention v4 (swapped QK^T, scalar online-SM) ------
// grid (32, B*H), 256 threads (4 waves x 16 q-rows). S^T = mfma(K,Q): lane holds
// 16 kv-values of ONE q-row (q = qw+lr) -> softmax reduce = in-reg + 2 shuffles.
// T13 defer-max skips the O-rescale unless max grows > 8 (log2 units).
__global__ __launch_bounds__(256)
void flash_attn(const bf16* __restrict__ qkv, const bf16* __restrict__ Vt,
                bf16* __restrict__ O) {
    __shared__ char smem[40960];   // K dbuf 16K | V dbuf 16K | P 4x2K
    int tid = threadIdx.x;
    int lane = tid & 63, w = tid >> 6;
    int lr = lane & 15, lq = lane >> 4;
    int bh = blockIdx.y, b = bh >> 4, h = bh & 15;
    int qt = (int)((blockIdx.x + blockIdx.y) & 31);   // balance causal depth across CUs
    int q0 = qt * 64;
    int qw = q0 + w * 16;
    const bf16* Qb = qkv + (size_t)(b*T_)*3072 + h*HD_;
    const bf16* Kb = Qb + 1024;
    const bf16* Vb = Vt + (size_t)bh * HD_ * T_;
    char* Pw = smem + 32768 + w*2048;

    int sc_   = (((lane & 7) ^ ((lane >> 3) & 7))) * 8;
    int srow_ = w*8 + (lane >> 3);

    s16x8 qf[2];
#pragma unroll
    for (int kk = 0; kk < 2; ++kk)
        qf[kk] = *reinterpret_cast<const s16x8*>(Qb + (size_t)(qw + lr)*3072 + kk*32 + lq*8);
    f32x4 od[4] = {};
    float mrun = -1e30f, lrun = 0.f;
    const float SLOG2E = 0.125f * 1.44269504088896f;
    int ntiles = qt + 1;

#define STAGE(bufi, tile) do {                                                          \
        int kv0s_ = (tile) * 64;                                                        \
        _Pragma("unroll")                                                               \
        for (int i_ = 0; i_ < 2; ++i_) {                                                \
            int rr_ = i_*32 + srow_;                                                    \
            async_cp16(Kb + (size_t)(kv0s_ + rr_)*3072 + sc_,                           \
                       smem + (bufi)*8192 + i_*4096 + w*1024);                          \
            async_cp16(Vb + (size_t)rr_*2048 + kv0s_ + sc_,                             \
                       smem + 16384 + (bufi)*8192 + i_*4096 + w*1024);                  \
        } } while (0)

    STAGE(0, 0);
    for (int it = 0; it < ntiles; ++it) {
        int curb = it & 1;
        int kv0 = it * 64;
        if (it + 1 < ntiles) {
            STAGE(curb ^ 1, it + 1);
            asm volatile("s_waitcnt vmcnt(4)" ::: "memory");
        } else {
            asm volatile("s_waitcnt vmcnt(0)" ::: "memory");
        }
        __builtin_amdgcn_sched_barrier(0);
        __builtin_amdgcn_s_barrier();
        __builtin_amdgcn_sched_barrier(0);
        const char* Kt = smem + curb*8192;
        const char* Vtl = smem + 16384 + curb*8192;
        f32x4 sc[4];
        __builtin_amdgcn_s_setprio(1);
#pragma unroll
        for (int n = 0; n < 4; ++n) {
            int row = n*16 + lr;
            s16x8 kf0 = *reinterpret_cast<const s16x8*>(Kt + row*128 + ((lq ^ (row&7)) << 4));
            s16x8 kf1 = *reinterpret_cast<const s16x8*>(Kt + row*128 + (((4+lq) ^ (row&7)) << 4));
            f32x4 z = {0.f, 0.f, 0.f, 0.f};
            z = MFMA16(kf0, qf[0], z);    // swapped: S^T, col=q(lr), row=kv
            z = MFMA16(kf1, qf[1], z);
            sc[n] = z;
        }
        __builtin_amdgcn_s_setprio(0);
        if (it == ntiles - 1) {   // causal mask on diagonal tile: kv > q
            int q = qw + lr;
#pragma unroll
            for (int n = 0; n < 4; ++n)
#pragma unroll
                for (int r = 0; r < 4; ++r)
                    if (kv0 + n*16 + lq*4 + r > q) sc[n][r] = -1e30f;
        }
        // row max: 15 in-reg + 2 shuffles (across lq)
        float mx01 = fmaxf(fmaxf(sc[0][0], sc[0][1]), fmaxf(sc[0][2], sc[0][3]));
        float mx1  = fmaxf(fmaxf(sc[1][0], sc[1][1]), fmaxf(sc[1][2], sc[1][3]));
        float mx2  = fmaxf(fmaxf(sc[2][0], sc[2][1]), fmaxf(sc[2][2], sc[2][3]));
        float mx3  = fmaxf(fmaxf(sc[3][0], sc[3][1]), fmaxf(sc[3][2], sc[3][3]));
        float pmax = fmaxf(fmaxf(mx01, mx1), fmaxf(mx2, mx3));
        pmax = fmaxf(pmax, __shfl_xor(pmax, 16));
        pmax = fmaxf(pmax, __shfl_xor(pmax, 32));
        float ps = pmax * SLOG2E;
        if (__ballot(ps > mrun + 8.f)) {     // T13 defer-max: rescale rarely
            float mn = fmaxf(mrun, ps);
            float corr = exp2f(mrun - mn);
            mrun = mn;
            lrun *= corr;
            float cR[4];
#pragma unroll
            for (int r = 0; r < 4; ++r) cR[r] = __shfl(corr, lq*4 + r);  // lr-dom -> od-row dom
#pragma unroll
            for (int nd = 0; nd < 4; ++nd)
#pragma unroll
                for (int r = 0; r < 4; ++r)
                    od[nd][r] *= cR[r];
        }
        float psum = 0.f;
#pragma unroll
        for (int n = 0; n < 4; ++n) {
            float p0 = exp2f(fmaf(sc[n][0], SLOG2E, -mrun));
            float p1 = exp2f(fmaf(sc[n][1], SLOG2E, -mrun));
            float p2 = exp2f(fmaf(sc[n][2], SLOG2E, -mrun));
            float p3 = exp2f(fmaf(sc[n][3], SLOG2E, -mrun));
            psum += (p0 + p1) + (p2 + p3);
            uint2 pk;
            pk.x = ((unsigned)f2bf(p1) << 16) | f2bf(p0);
            pk.y = ((unsigned)f2bf(p3) << 16) | f2bf(p2);
            int bo = (lr*128 + n*32 + lq*8) ^ ((lr & 7) << 4);
            *reinterpret_cast<uint2*>(Pw + bo) = pk;    // P[q=lr][kv], b64 write
        }
        psum += __shfl_xor(psum, 16);
        psum += __shfl_xor(psum, 32);
        lrun += psum;
        asm volatile("" ::: "memory");   // keep P stores before pa reads
        s16x8 pa[2];
#pragma unroll
        for (int kk = 0; kk < 2; ++kk) {
            int bo = (lr*128 + kk*64 + lq*16) ^ ((lr & 7) << 4);
            pa[kk] = *reinterpret_cast<const s16x8*>(Pw + bo);
        }
        __builtin_amdgcn_s_setprio(1);
#pragma unroll
        for (int nd = 0; nd < 4; ++nd) {
            int row = nd*16 + lr;
            s16x8 vf0 = *reinterpret_cast<const s16x8*>(Vtl + row*128 + ((lq ^ (row&7)) << 4));
            s16x8 vf1 = *reinterpret_cast<const s16x8*>(Vtl + row*128 + (((4+lq) ^ (row&7)) << 4));
            od[nd] = MFMA16(pa[0], vf0, od[nd]);
            od[nd] = MFMA16(pa[1], vf1, od[nd]);
        }
        __builtin_amdgcn_s_setprio(0);
        __builtin_amdgcn_sched_barrier(0);
        __builtin_amdgcn_s_barrier();   // reads done before next STAGE overwrites
        __builtin_amdgcn_sched_barrier(0);
    }
#undef STAGE
    float lR[4];
#pragma unroll
    for (int r = 0; r < 4; ++r) lR[r] = 1.0f / __shfl(lrun, lq*4 + r);
#pragma unroll
    for (int nd = 0; nd < 4; ++nd) {
#pragma unroll
        for (int r = 0; r < 4; ++r) {
            int row = qw + lq*4 + r;
            O[(size_t)(b*T_ + row)*E_ + h*HD_ + nd*16 + lr] = __float2bfloat16(od[nd][r] * lR[r]);
        }
    }
}

// ---------------- launch ----------------
extern "C" void kernel_launch(void* const* d_in, const int* in_sizes, int n_in,
                              void* d_out, int out_size, void* d_ws, size_t ws_size,
                              hipStream_t stream) {
    const float* x   = (const float*)d_in[0];
    const float* Wk  = (const float*)d_in[1];
    const float* Wq  = (const float*)d_in[2];
    const float* Wv  = (const float*)d_in[3];
    const float* Wp  = (const float*)d_in[4];
    const float* bp  = (const float*)d_in[5];
    const float* W1  = (const float*)d_in[6];
    const float* b1  = (const float*)d_in[7];
    const float* W2  = (const float*)d_in[8];
    const float* b2  = (const float*)d_in[9];
    const float* g1  = (const float*)d_in[10];
    const float* be1 = (const float*)d_in[11];
    const float* g2  = (const float*)d_in[12];
    const float* be2 = (const float*)d_in[13];
    float* out = (float*)d_out;

    char* ws = (char*)d_ws;
    bf16* Wqkv_t = (bf16*)(ws + 0);          //  6 MB [3072][1024] (+Wp_t after)
    bf16* Wp_t   = (bf16*)(ws + 6291456);    //  2 MB [1024][1024]
    bf16* W1_t   = (bf16*)(ws + 8388608);    //  8 MB [4096][1024]
    bf16* W2_t   = (bf16*)(ws + 16777216);   //  8 MB [1024][4096]
    bf16* h      = (bf16*)(ws + 25165824);   //  8 MB [4096][1024] (reused as h2)
    bf16* qkv    = (bf16*)(ws + 33554432);   // 24 MB [4096][3072]
    bf16* Vt     = (bf16*)(ws + 58720256);   //  8 MB [B,H,HD,T]
    bf16* attnO  = (bf16*)(ws + 67108864);   //  8 MB [4096][1024]
    bf16* ff1    = (bf16*)(ws + 33554432);   // 32 MB, reuses qkv+Vt (dead after flash)
    float* x2    = (ws_size >= 92274688) ? (float*)(ws + 75497472) : out;  // 16 MB

    dim3 tb(32, 8);
    transpose_cvt4<<<dim3(32, 32, 4), tb, 0, stream>>>(Wq, Wk, Wv, Wp, Wqkv_t);
    transpose_cvt<<<dim3(128, 32), tb, 0, stream>>>(W1, W1_t, 1024, 4096);
    transpose_cvt<<<dim3(32, 128), tb, 0, stream>>>(W2, W2_t, 4096, 1024);

    ln_kernel<<<NT, 256, 0, stream>>>(x, g1, be1, h);
    gemm_t<128,0><<<dim3(24, 32), 256, 0, stream>>>(h, Wqkv_t, qkv, nullptr, nullptr, NT, 3072, 1024);
    v_transpose<<<dim3(64, 2, 32), tb, 0, stream>>>(qkv, Vt);
    flash_attn<<<dim3(32, 32), 256, 0, stream>>>(qkv, Vt, attnO);
    gemm_t<64,1><<<dim3(16, 32), 256, 0, stream>>>(attnO, Wp_t, x2, bp, x, NT, 1024, 1024);
    ln_kernel<<<NT, 256, 0, stream>>>(x2, g2, be2, h);
    gemm_t<128,2><<<dim3(32, 32), 256, 0, stream>>>(h, W1_t, ff1, b1, nullptr, NT, 4096, 1024);
    gemm_t<64,1><<<dim3(16, 32), 256, 0, stream>>>(ff1, W2_t, out, b2, x2, NT, 1024, 4096);
}

// Round 5
// 229.689 us; speedup vs baseline: 2.1295x; 1.0458x over previous
//
#include <hip/hip_runtime.h>
#include <hip/hip_bf16.h>

#define B_ 2
#define T_ 2048
#define E_ 1024
#define H_ 16
#define HD_ 64
#define NT (B_*T_)

typedef __attribute__((ext_vector_type(8))) short s16x8;
typedef __attribute__((ext_vector_type(4))) float f32x4;
typedef __attribute__((ext_vector_type(4))) unsigned int u32x4;

using bf16 = __hip_bfloat16;

#define MFMA16(a,b,c) __builtin_amdgcn_mfma_f32_16x16x32_bf16(a,b,c,0,0,0)

__device__ inline unsigned short f2bf(float f) {
    bf16 h = __float2bfloat16(f);
    return *reinterpret_cast<unsigned short*>(&h);
}

__device__ __forceinline__ unsigned cvt_pk_bf16(float lo, float hi) {
    unsigned r;
    asm("v_cvt_pk_bf16_f32 %0, %1, %2" : "=v"(r) : "v"(lo), "v"(hi));
    return r;
}

// async global->LDS, 16B per lane. LDS dest is wave-uniform base + lane*16.
__device__ __forceinline__ void async_cp16(const void* g, void* l) {
    __builtin_amdgcn_global_load_lds((const __attribute__((address_space(1))) void*)g,
                                     (__attribute__((address_space(3))) void*)l,
                                     16, 0, 0);
}

// ---------------- all weight transposes + fp32->bf16, one dispatch ----------------
__global__ __launch_bounds__(256) void transpose_all(const float* __restrict__ Wq,
                                                     const float* __restrict__ Wk,
                                                     const float* __restrict__ Wv,
                                                     const float* __restrict__ Wp,
                                                     const float* __restrict__ W1,
                                                     const float* __restrict__ W2,
                                                     bf16* __restrict__ Wqkv_t,
                                                     bf16* __restrict__ W1_t,
                                                     bf16* __restrict__ W2_t) {
    __shared__ float tile[32][33];
    int id = blockIdx.x;
    const float* src; bf16* dst; int K, N, n0, k0;
    if (id < 4096) {
        int z = id >> 10, t = id & 1023;
        src = z == 0 ? Wq : z == 1 ? Wk : z == 2 ? Wv : Wp;
        dst = Wqkv_t + (size_t)z * 1048576;
        K = 1024; N = 1024; n0 = (t & 31) * 32; k0 = (t >> 5) * 32;
    } else if (id < 8192) {
        int t = id - 4096; src = W1; dst = W1_t; K = 1024; N = 4096;
        n0 = (t & 127) * 32; k0 = (t >> 7) * 32;
    } else {
        int t = id - 8192; src = W2; dst = W2_t; K = 4096; N = 1024;
        n0 = (t & 31) * 32; k0 = (t >> 5) * 32;
    }
    int tx = threadIdx.x, ty = threadIdx.y;
#pragma unroll
    for (int i = 0; i < 4; ++i)
        tile[ty + i*8][tx] = src[(size_t)(k0 + ty + i*8)*N + n0 + tx];
    __syncthreads();
#pragma unroll
    for (int i = 0; i < 4; ++i)
        dst[(size_t)(n0 + ty + i*8)*K + k0 + tx] = __float2bfloat16(tile[tx][ty + i*8]);
}

// ---------------- LayerNorm (fp32 in -> bf16 out) ----------------
__global__ __launch_bounds__(256) void ln_kernel(const float* __restrict__ x,
                                                 const float* __restrict__ g,
                                                 const float* __restrict__ b,
                                                 bf16* __restrict__ h) {
    int row = blockIdx.x;
    int tid = threadIdx.x;
    const float4 xv = *reinterpret_cast<const float4*>(x + (size_t)row*E_ + tid*4);
    float s  = xv.x + xv.y + xv.z + xv.w;
    float sq = xv.x*xv.x + xv.y*xv.y + xv.z*xv.z + xv.w*xv.w;
#pragma unroll
    for (int o = 32; o > 0; o >>= 1) { s += __shfl_xor(s, o); sq += __shfl_xor(sq, o); }
    __shared__ float red[8];
    int w = tid >> 6, lane = tid & 63;
    if (lane == 0) { red[w] = s; red[4 + w] = sq; }
    __syncthreads();
    float S = red[0] + red[1] + red[2] + red[3];
    float Q = red[4] + red[5] + red[6] + red[7];
    float mu = S * (1.0f/E_);
    float var = Q * (1.0f/E_) - mu*mu;
    float rs = rsqrtf(var + 1e-5f);
    const float4 gv = *reinterpret_cast<const float4*>(g + tid*4);
    const float4 bv = *reinterpret_cast<const float4*>(b + tid*4);
    ushort4 o4;
    o4.x = f2bf((xv.x - mu)*rs*gv.x + bv.x);
    o4.y = f2bf((xv.y - mu)*rs*gv.y + bv.y);
    o4.z = f2bf((xv.z - mu)*rs*gv.z + bv.z);
    o4.w = f2bf((xv.w - mu)*rs*gv.w + bv.w);
    *reinterpret_cast<ushort4*>(h + (size_t)row*E_ + tid*4) = o4;
}

// ---------------- 128xBN bf16 MFMA GEMM, BK=64, XOR-swizzled LDS ----------------
template<int BN, int EPI>
__global__ __launch_bounds__(256)
void gemm_t(const bf16* __restrict__ A, const bf16* __restrict__ Bt, void* Cout,
            const float* __restrict__ bias, const float* res,
            int M, int N, int K) {
    constexpr int NB = BN / 32;
    constexpr int HALF = BN / 2;
    __shared__ bf16 As[128*64];
    __shared__ bf16 Bs[BN*64];
    int tid = threadIdx.x;
    int lane = tid & 63, w = tid >> 6;
    int wr = w >> 1, wc = w & 1;
    int m0 = blockIdx.y * 128, n0 = blockIdx.x * BN;
    int lr = lane & 15, lq = lane >> 4;
    f32x4 acc[4][NB] = {};
    int srow = w*8 + (lane >> 3);
    int schunk = ((lane & 7) ^ (srow & 7)) * 8;
    const bf16* Ap = A  + (size_t)(m0 + srow)*K + schunk;
    const bf16* Bp = Bt + (size_t)(n0 + srow)*K + schunk;
    for (int k0 = 0; k0 < K; k0 += 64) {
#pragma unroll
        for (int i = 0; i < 4; ++i)
            async_cp16(Ap + (size_t)(i*32)*K + k0, (char*)As + i*4096 + w*1024);
#pragma unroll
        for (int i = 0; i < BN/32; ++i)
            async_cp16(Bp + (size_t)(i*32)*K + k0, (char*)Bs + i*4096 + w*1024);
        __syncthreads();
        const char* Asb = (const char*)As;
        const char* Bsb = (const char*)Bs;
        s16x8 af[2][4], bfr[2][NB];
#pragma unroll
        for (int m = 0; m < 4; ++m) {
            int row = wr*64 + m*16 + lr;
            int base = row*128, sw = (row & 7) << 4;
#pragma unroll
            for (int kk = 0; kk < 2; ++kk)
                af[kk][m] = *reinterpret_cast<const s16x8*>(Asb + base + ((kk*64 + lq*16) ^ sw));
        }
#pragma unroll
        for (int n = 0; n < NB; ++n) {
            int row = wc*HALF + n*16 + lr;
            int base = row*128, sw = (row & 7) << 4;
#pragma unroll
            for (int kk = 0; kk < 2; ++kk)
                bfr[kk][n] = *reinterpret_cast<const s16x8*>(Bsb + base + ((kk*64 + lq*16) ^ sw));
        }
        __builtin_amdgcn_s_setprio(1);
#pragma unroll
        for (int kk = 0; kk < 2; ++kk)
#pragma unroll
            for (int m = 0; m < 4; ++m)
#pragma unroll
                for (int n = 0; n < NB; ++n)
                    acc[m][n] = MFMA16(af[kk][m], bfr[kk][n], acc[m][n]);
        __builtin_amdgcn_s_setprio(0);
        __syncthreads();
    }
#pragma unroll
    for (int m = 0; m < 4; ++m) {
#pragma unroll
        for (int n = 0; n < NB; ++n) {
            int col = n0 + wc*HALF + n*16 + lr;
#pragma unroll
            for (int r = 0; r < 4; ++r) {
                int row = m0 + wr*64 + m*16 + lq*4 + r;
                float v = acc[m][n][r];
                if (EPI == 0) {
                    reinterpret_cast<bf16*>(Cout)[(size_t)row*N + col] = __float2bfloat16(v);
                } else if (EPI == 1) {
                    reinterpret_cast<float*>(Cout)[(size_t)row*N + col] =
                        v + bias[col] + res[(size_t)row*N + col];
                } else {
                    v += bias[col];
                    v = v > 0.f ? v : 0.f;
                    reinterpret_cast<bf16*>(Cout)[(size_t)row*N + col] = __float2bfloat16(v);
                }
            }
        }
    }
}

// ---------------- V transpose: qkv v-section -> Vt [B,H,HD,T] ----------------
__global__ __launch_bounds__(256) void v_transpose(const bf16* __restrict__ qkv,
                                                   bf16* __restrict__ Vt) {
    __shared__ unsigned short tile[32][33];
    int tx = threadIdx.x, ty = threadIdx.y;
    int bh = blockIdx.z;
    int b = bh >> 4, h = bh & 15;
    int t0 = blockIdx.x * 32, d0 = blockIdx.y * 32;
    const unsigned short* src = reinterpret_cast<const unsigned short*>(qkv);
#pragma unroll
    for (int i = 0; i < 4; ++i)
        tile[ty + i*8][tx] = src[(size_t)(b*T_ + t0 + ty + i*8)*3072 + 2048 + h*64 + d0 + tx];
    __syncthreads();
    unsigned short* dst = reinterpret_cast<unsigned short*>(Vt);
#pragma unroll
    for (int i = 0; i < 4; ++i)
        dst[(size_t)(bh*64 + d0 + ty + i*8)*T_ + t0 + tx] = tile[tx][ty + i*8];
}

// ---------------- causal flash attention v5: paired q-tiles ----------------
// grid (16, B*H), 256 threads. Block handles q-tiles {qtA, 31-qtA} interleaved:
// one K/V stage serves both. Co-resident blocks (id, id+256) get complementary
// qtA so every CU sums to 49 steps. LDS 48K: K dbuf | V dbuf | P_A | P_B.
__global__ __launch_bounds__(256)
void flash_attn(const bf16* __restrict__ qkv, const bf16* __restrict__ Vt,
                bf16* __restrict__ O) {
    __shared__ char smem[49152];
    int tid = threadIdx.x;
    int lane = tid & 63, w = tid >> 6;
    int lr = lane & 15, lq = lane >> 4;
    int bh = blockIdx.y, b = bh >> 4, h = bh & 15;
    int c = (int)((blockIdx.x + bh) & 15);
    int qtA = (bh & 16) ? (15 - c) : c;     // shallow 0..15
    int qtB = 31 - qtA;                     // deep 16..31
    int ntB = qtB + 1;
    int qwA = qtA*64 + w*16, qwB = qtB*64 + w*16;
    const bf16* Qb = qkv + (size_t)(b*T_)*3072 + h*HD_;
    const bf16* Kb = Qb + 1024;
    const bf16* Vb = Vt + (size_t)bh * HD_ * T_;
    char* PwA = smem + 32768 + w*2048;
    char* PwB = smem + 40960 + w*2048;

    int sc_   = (((lane & 7) ^ ((lane >> 3) & 7))) * 8;
    int srow_ = w*8 + (lane >> 3);

    s16x8 qfA[2], qfB[2];
#pragma unroll
    for (int kk = 0; kk < 2; ++kk) {
        qfA[kk] = *reinterpret_cast<const s16x8*>(Qb + (size_t)(qwA + lr)*3072 + kk*32 + lq*8);
        qfB[kk] = *reinterpret_cast<const s16x8*>(Qb + (size_t)(qwB + lr)*3072 + kk*32 + lq*8);
    }
    f32x4 odA[4] = {}, odB[4] = {};
    float mA = -1e30f, lA = 0.f, mB = -1e30f, lB = 0.f;
    const float SLOG2E = 0.125f * 1.44269504088896f;

    auto step = [&](f32x4 (&od)[4], float& mrun, float& lrun, char* Pw,
                    const s16x8 (&qf)[2], int qw, bool diag,
                    const char* Kt, const char* Vtl, int kv0) {
        f32x4 sc[4];
        __builtin_amdgcn_s_setprio(1);
#pragma unroll
        for (int n = 0; n < 4; ++n) {
            int row = n*16 + lr;
            int ko = row*128 + ((lq ^ (row & 7)) << 4);
            s16x8 kf0 = *reinterpret_cast<const s16x8*>(Kt + ko);
            s16x8 kf1 = *reinterpret_cast<const s16x8*>(Kt + (ko ^ 64));
            f32x4 z = {0.f, 0.f, 0.f, 0.f};
            z = MFMA16(kf0, qf[0], z);    // S^T: col=q(lr), row=kv
            z = MFMA16(kf1, qf[1], z);
            sc[n] = z;
        }
        __builtin_amdgcn_s_setprio(0);
        if (diag) {
            int q = qw + lr;
#pragma unroll
            for (int n = 0; n < 4; ++n)
#pragma unroll
                for (int r = 0; r < 4; ++r)
                    if (kv0 + n*16 + lq*4 + r > q) sc[n][r] = -1e30f;
        }
        float mx0 = fmaxf(fmaxf(sc[0][0], sc[0][1]), fmaxf(sc[0][2], sc[0][3]));
        float mx1 = fmaxf(fmaxf(sc[1][0], sc[1][1]), fmaxf(sc[1][2], sc[1][3]));
        float mx2 = fmaxf(fmaxf(sc[2][0], sc[2][1]), fmaxf(sc[2][2], sc[2][3]));
        float mx3 = fmaxf(fmaxf(sc[3][0], sc[3][1]), fmaxf(sc[3][2], sc[3][3]));
        float pmax = fmaxf(fmaxf(mx0, mx1), fmaxf(mx2, mx3));
        pmax = fmaxf(pmax, __shfl_xor(pmax, 16));
        pmax = fmaxf(pmax, __shfl_xor(pmax, 32));
        float ps = pmax * SLOG2E;
        if (__ballot(ps > mrun + 8.f)) {     // T13 defer-max
            float mn = fmaxf(mrun, ps);
            float corr = exp2f(mrun - mn);
            mrun = mn;
            lrun *= corr;
            float cR[4];
#pragma unroll
            for (int r = 0; r < 4; ++r) cR[r] = __shfl(corr, lq*4 + r);
#pragma unroll
            for (int nd = 0; nd < 4; ++nd)
#pragma unroll
                for (int r = 0; r < 4; ++r)
                    od[nd][r] *= cR[r];
        }
        float psum = 0.f;
#pragma unroll
        for (int n = 0; n < 4; ++n) {
            float p0 = exp2f(fmaf(sc[n][0], SLOG2E, -mrun));
            float p1 = exp2f(fmaf(sc[n][1], SLOG2E, -mrun));
            float p2 = exp2f(fmaf(sc[n][2], SLOG2E, -mrun));
            float p3 = exp2f(fmaf(sc[n][3], SLOG2E, -mrun));
            psum += (p0 + p1) + (p2 + p3);
            uint2 pk;
            pk.x = cvt_pk_bf16(p0, p1);
            pk.y = cvt_pk_bf16(p2, p3);
            int bo = (lr*128 + n*32 + lq*8) ^ ((lr & 7) << 4);
            *reinterpret_cast<uint2*>(Pw + bo) = pk;    // P[q=lr][kv]
        }
        psum += __shfl_xor(psum, 16);
        psum += __shfl_xor(psum, 32);
        lrun += psum;
        asm volatile("" ::: "memory");   // keep P stores before pa reads
        s16x8 pa[2];
#pragma unroll
        for (int kk = 0; kk < 2; ++kk) {
            int bo = (lr*128 + kk*64 + lq*16) ^ ((lr & 7) << 4);
            pa[kk] = *reinterpret_cast<const s16x8*>(Pw + bo);
        }
        __builtin_amdgcn_s_setprio(1);
#pragma unroll
        for (int nd = 0; nd < 4; ++nd) {
            int row = nd*16 + lr;
            int vo = row*128 + ((lq ^ (row & 7)) << 4);
            s16x8 vf0 = *reinterpret_cast<const s16x8*>(Vtl + vo);
            s16x8 vf1 = *reinterpret_cast<const s16x8*>(Vtl + (vo ^ 64));
            od[nd] = MFMA16(pa[0], vf0, od[nd]);
            od[nd] = MFMA16(pa[1], vf1, od[nd]);
        }
        __builtin_amdgcn_s_setprio(0);
    };

#define STAGE(bufi, tile) do {                                                          \
        int kv0s_ = (tile) * 64;                                                        \
        _Pragma("unroll")                                                               \
        for (int i_ = 0; i_ < 2; ++i_) {                                                \
            int rr_ = i_*32 + srow_;                                                    \
            async_cp16(Kb + (size_t)(kv0s_ + rr_)*3072 + sc_,                           \
                       smem + (bufi)*8192 + i_*4096 + w*1024);                          \
            async_cp16(Vb + (size_t)rr_*2048 + kv0s_ + sc_,                             \
                       smem + 16384 + (bufi)*8192 + i_*4096 + w*1024);                  \
        } } while (0)

    STAGE(0, 0);
    for (int it = 0; it < ntB; ++it) {
        int curb = it & 1;
        int kv0 = it * 64;
        if (it + 1 < ntB) {
            STAGE(curb ^ 1, it + 1);
            asm volatile("s_waitcnt vmcnt(4)" ::: "memory");
        } else {
            asm volatile("s_waitcnt vmcnt(0)" ::: "memory");
        }
        __builtin_amdgcn_sched_barrier(0);
        __builtin_amdgcn_s_barrier();
        __builtin_amdgcn_sched_barrier(0);
        const char* Kt = smem + curb*8192;
        const char* Vtl = smem + 16384 + curb*8192;
        step(odB, mB, lB, PwB, qfB, qwB, it == qtB, Kt, Vtl, kv0);
        if (it <= qtA)
            step(odA, mA, lA, PwA, qfA, qwA, it == qtA, Kt, Vtl, kv0);
        __builtin_amdgcn_sched_barrier(0);
        __builtin_amdgcn_s_barrier();   // reads done before next STAGE overwrites
        __builtin_amdgcn_sched_barrier(0);
    }
#undef STAGE
    float lRA[4], lRB[4];
#pragma unroll
    for (int r = 0; r < 4; ++r) {
        lRA[r] = 1.0f / __shfl(lA, lq*4 + r);
        lRB[r] = 1.0f / __shfl(lB, lq*4 + r);
    }
#pragma unroll
    for (int nd = 0; nd < 4; ++nd) {
#pragma unroll
        for (int r = 0; r < 4; ++r) {
            int rowA = qwA + lq*4 + r;
            int rowB = qwB + lq*4 + r;
            int col = h*HD_ + nd*16 + lr;
            O[(size_t)(b*T_ + rowA)*E_ + col] = __float2bfloat16(odA[nd][r] * lRA[r]);
            O[(size_t)(b*T_ + rowB)*E_ + col] = __float2bfloat16(odB[nd][r] * lRB[r]);
        }
    }
}

// ---------------- launch ----------------
extern "C" void kernel_launch(void* const* d_in, const int* in_sizes, int n_in,
                              void* d_out, int out_size, void* d_ws, size_t ws_size,
                              hipStream_t stream) {
    const float* x   = (const float*)d_in[0];
    const float* Wk  = (const float*)d_in[1];
    const float* Wq  = (const float*)d_in[2];
    const float* Wv  = (const float*)d_in[3];
    const float* Wp  = (const float*)d_in[4];
    const float* bp  = (const float*)d_in[5];
    const float* W1  = (const float*)d_in[6];
    const float* b1  = (const float*)d_in[7];
    const float* W2  = (const float*)d_in[8];
    const float* b2  = (const float*)d_in[9];
    const float* g1  = (const float*)d_in[10];
    const float* be1 = (const float*)d_in[11];
    const float* g2  = (const float*)d_in[12];
    const float* be2 = (const float*)d_in[13];
    float* out = (float*)d_out;

    char* ws = (char*)d_ws;
    bf16* Wqkv_t = (bf16*)(ws + 0);          //  6 MB [3072][1024] (+Wp_t after)
    bf16* Wp_t   = (bf16*)(ws + 6291456);    //  2 MB [1024][1024]
    bf16* W1_t   = (bf16*)(ws + 8388608);    //  8 MB [4096][1024]
    bf16* W2_t   = (bf16*)(ws + 16777216);   //  8 MB [1024][4096]
    bf16* h      = (bf16*)(ws + 25165824);   //  8 MB [4096][1024] (reused as h2)
    bf16* qkv    = (bf16*)(ws + 33554432);   // 24 MB [4096][3072]
    bf16* Vt     = (bf16*)(ws + 58720256);   //  8 MB [B,H,HD,T]
    bf16* attnO  = (bf16*)(ws + 67108864);   //  8 MB [4096][1024]
    bf16* ff1    = (bf16*)(ws + 33554432);   // 32 MB, reuses qkv+Vt (dead after flash)
    float* x2    = (ws_size >= 92274688) ? (float*)(ws + 75497472) : out;  // 16 MB

    dim3 tb(32, 8);
    transpose_all<<<12288, tb, 0, stream>>>(Wq, Wk, Wv, Wp, W1, W2, Wqkv_t, W1_t, W2_t);

    ln_kernel<<<NT, 256, 0, stream>>>(x, g1, be1, h);
    gemm_t<128,0><<<dim3(24, 32), 256, 0, stream>>>(h, Wqkv_t, qkv, nullptr, nullptr, NT, 3072, 1024);
    v_transpose<<<dim3(64, 2, 32), tb, 0, stream>>>(qkv, Vt);
    flash_attn<<<dim3(16, 32), 256, 0, stream>>>(qkv, Vt, attnO);
    gemm_t<64,1><<<dim3(16, 32), 256, 0, stream>>>(attnO, Wp_t, x2, bp, x, NT, 1024, 1024);
    ln_kernel<<<NT, 256, 0, stream>>>(x2, g2, be2, h);
    gemm_t<128,2><<<dim3(32, 32), 256, 0, stream>>>(h, W1_t, ff1, b1, nullptr, NT, 4096, 1024);
    gemm_t<64,1><<<dim3(16, 32), 256, 0, stream>>>(ff1, W2_t, out, b2, x2, NT, 1024, 4096);
}

// Round 6
// 226.321 us; speedup vs baseline: 2.1612x; 1.0149x over previous
//
#include <hip/hip_runtime.h>
#include <hip/hip_bf16.h>

#define B_ 2
#define T_ 2048
#define E_ 1024
#define H_ 16
#define HD_ 64
#define NT (B_*T_)

typedef __attribute__((ext_vector_type(8))) short s16x8;
typedef __attribute__((ext_vector_type(4))) float f32x4;
typedef __attribute__((ext_vector_type(4))) unsigned int u32x4;

using bf16 = __hip_bfloat16;

#define MFMA16(a,b,c) __builtin_amdgcn_mfma_f32_16x16x32_bf16(a,b,c,0,0,0)

__device__ inline unsigned short f2bf(float f) {
    bf16 h = __float2bfloat16(f);
    return *reinterpret_cast<unsigned short*>(&h);
}

__device__ __forceinline__ unsigned cvt_pk_bf16(float lo, float hi) {
    unsigned r;
    asm("v_cvt_pk_bf16_f32 %0, %1, %2" : "=v"(r) : "v"(lo), "v"(hi));
    return r;
}

// async global->LDS, 16B per lane. LDS dest is wave-uniform base + lane*16.
__device__ __forceinline__ void async_cp16(const void* g, void* l) {
    __builtin_amdgcn_global_load_lds((const __attribute__((address_space(1))) void*)g,
                                     (__attribute__((address_space(3))) void*)l,
                                     16, 0, 0);
}

// ---------------- all weight transposes + fp32->bf16, one dispatch ----------------
__global__ __launch_bounds__(256) void transpose_all(const float* __restrict__ Wq,
                                                     const float* __restrict__ Wk,
                                                     const float* __restrict__ Wv,
                                                     const float* __restrict__ Wp,
                                                     const float* __restrict__ W1,
                                                     const float* __restrict__ W2,
                                                     bf16* __restrict__ Wqkv_t,
                                                     bf16* __restrict__ W1_t,
                                                     bf16* __restrict__ W2_t) {
    __shared__ float tile[32][33];
    int id = blockIdx.x;
    const float* src; bf16* dst; int K, N, n0, k0;
    if (id < 4096) {
        int z = id >> 10, t = id & 1023;
        src = z == 0 ? Wq : z == 1 ? Wk : z == 2 ? Wv : Wp;
        dst = Wqkv_t + (size_t)z * 1048576;
        K = 1024; N = 1024; n0 = (t & 31) * 32; k0 = (t >> 5) * 32;
    } else if (id < 8192) {
        int t = id - 4096; src = W1; dst = W1_t; K = 1024; N = 4096;
        n0 = (t & 127) * 32; k0 = (t >> 7) * 32;
    } else {
        int t = id - 8192; src = W2; dst = W2_t; K = 4096; N = 1024;
        n0 = (t & 31) * 32; k0 = (t >> 5) * 32;
    }
    int tx = threadIdx.x, ty = threadIdx.y;
#pragma unroll
    for (int i = 0; i < 4; ++i)
        tile[ty + i*8][tx] = src[(size_t)(k0 + ty + i*8)*N + n0 + tx];
    __syncthreads();
#pragma unroll
    for (int i = 0; i < 4; ++i)
        dst[(size_t)(n0 + ty + i*8)*K + k0 + tx] = __float2bfloat16(tile[tx][ty + i*8]);
}

// ---------------- LayerNorm (fp32 in -> bf16 out) ----------------
__global__ __launch_bounds__(256) void ln_kernel(const float* __restrict__ x,
                                                 const float* __restrict__ g,
                                                 const float* __restrict__ b,
                                                 bf16* __restrict__ h) {
    int row = blockIdx.x;
    int tid = threadIdx.x;
    const float4 xv = *reinterpret_cast<const float4*>(x + (size_t)row*E_ + tid*4);
    float s  = xv.x + xv.y + xv.z + xv.w;
    float sq = xv.x*xv.x + xv.y*xv.y + xv.z*xv.z + xv.w*xv.w;
#pragma unroll
    for (int o = 32; o > 0; o >>= 1) { s += __shfl_xor(s, o); sq += __shfl_xor(sq, o); }
    __shared__ float red[8];
    int w = tid >> 6, lane = tid & 63;
    if (lane == 0) { red[w] = s; red[4 + w] = sq; }
    __syncthreads();
    float S = red[0] + red[1] + red[2] + red[3];
    float Q = red[4] + red[5] + red[6] + red[7];
    float mu = S * (1.0f/E_);
    float var = Q * (1.0f/E_) - mu*mu;
    float rs = rsqrtf(var + 1e-5f);
    const float4 gv = *reinterpret_cast<const float4*>(g + tid*4);
    const float4 bv = *reinterpret_cast<const float4*>(b + tid*4);
    ushort4 o4;
    o4.x = f2bf((xv.x - mu)*rs*gv.x + bv.x);
    o4.y = f2bf((xv.y - mu)*rs*gv.y + bv.y);
    o4.z = f2bf((xv.z - mu)*rs*gv.z + bv.z);
    o4.w = f2bf((xv.w - mu)*rs*gv.w + bv.w);
    *reinterpret_cast<ushort4*>(h + (size_t)row*E_ + tid*4) = o4;
}

// ---------------- 128xBN bf16 MFMA GEMM, BK=64, XOR-swizzled LDS, XCD-chunked ----
// T1: remap hw block id -> work id so XCD k owns a contiguous m-panel-major chunk
// (requires nwg % 8 == 0 -- all our grids satisfy). A-panels then live in ONE L2.
template<int BN, int EPI>
__global__ __launch_bounds__(256)
void gemm_t(const bf16* __restrict__ A, const bf16* __restrict__ Bt, void* Cout,
            const float* __restrict__ bias, const float* res,
            int M, int N, int K) {
    constexpr int NB = BN / 32;
    constexpr int HALF = BN / 2;
    __shared__ bf16 As[128*64];
    __shared__ bf16 Bs[BN*64];
    int tid = threadIdx.x;
    int lane = tid & 63, w = tid >> 6;
    int wr = w >> 1, wc = w & 1;
    int nbx = gridDim.x;
    int hid = blockIdx.y * nbx + blockIdx.x;
    int cpx = (nbx * gridDim.y) >> 3;
    int nid = (hid & 7) * cpx + (hid >> 3);     // XCD-chunked (m157, bijective)
    int m0 = (nid / nbx) * 128, n0 = (nid % nbx) * BN;
    int lr = lane & 15, lq = lane >> 4;
    f32x4 acc[4][NB] = {};
    int srow = w*8 + (lane >> 3);
    int schunk = ((lane & 7) ^ (srow & 7)) * 8;
    const bf16* Ap = A  + (size_t)(m0 + srow)*K + schunk;
    const bf16* Bp = Bt + (size_t)(n0 + srow)*K + schunk;
    for (int k0 = 0; k0 < K; k0 += 64) {
#pragma unroll
        for (int i = 0; i < 4; ++i)
            async_cp16(Ap + (size_t)(i*32)*K + k0, (char*)As + i*4096 + w*1024);
#pragma unroll
        for (int i = 0; i < BN/32; ++i)
            async_cp16(Bp + (size_t)(i*32)*K + k0, (char*)Bs + i*4096 + w*1024);
        __syncthreads();
        const char* Asb = (const char*)As;
        const char* Bsb = (const char*)Bs;
        s16x8 af[2][4], bfr[2][NB];
#pragma unroll
        for (int m = 0; m < 4; ++m) {
            int row = wr*64 + m*16 + lr;
            int base = row*128, sw = (row & 7) << 4;
#pragma unroll
            for (int kk = 0; kk < 2; ++kk)
                af[kk][m] = *reinterpret_cast<const s16x8*>(Asb + base + ((kk*64 + lq*16) ^ sw));
        }
#pragma unroll
        for (int n = 0; n < NB; ++n) {
            int row = wc*HALF + n*16 + lr;
            int base = row*128, sw = (row & 7) << 4;
#pragma unroll
            for (int kk = 0; kk < 2; ++kk)
                bfr[kk][n] = *reinterpret_cast<const s16x8*>(Bsb + base + ((kk*64 + lq*16) ^ sw));
        }
        __builtin_amdgcn_s_setprio(1);
#pragma unroll
        for (int kk = 0; kk < 2; ++kk)
#pragma unroll
            for (int m = 0; m < 4; ++m)
#pragma unroll
                for (int n = 0; n < NB; ++n)
                    acc[m][n] = MFMA16(af[kk][m], bfr[kk][n], acc[m][n]);
        __builtin_amdgcn_s_setprio(0);
        __syncthreads();
    }
#pragma unroll
    for (int m = 0; m < 4; ++m) {
#pragma unroll
        for (int n = 0; n < NB; ++n) {
            int col = n0 + wc*HALF + n*16 + lr;
#pragma unroll
            for (int r = 0; r < 4; ++r) {
                int row = m0 + wr*64 + m*16 + lq*4 + r;
                float v = acc[m][n][r];
                if (EPI == 0) {
                    reinterpret_cast<bf16*>(Cout)[(size_t)row*N + col] = __float2bfloat16(v);
                } else if (EPI == 1) {
                    reinterpret_cast<float*>(Cout)[(size_t)row*N + col] =
                        v + bias[col] + res[(size_t)row*N + col];
                } else {
                    v += bias[col];
                    v = v > 0.f ? v : 0.f;
                    reinterpret_cast<bf16*>(Cout)[(size_t)row*N + col] = __float2bfloat16(v);
                }
            }
        }
    }
}

// ---------------- V transpose: qkv v-section -> Vt [B,H,HD,T] ----------------
__global__ __launch_bounds__(256) void v_transpose(const bf16* __restrict__ qkv,
                                                   bf16* __restrict__ Vt) {
    __shared__ unsigned short tile[32][33];
    int tx = threadIdx.x, ty = threadIdx.y;
    int bh = blockIdx.z;
    int b = bh >> 4, h = bh & 15;
    int t0 = blockIdx.x * 32, d0 = blockIdx.y * 32;
    const unsigned short* src = reinterpret_cast<const unsigned short*>(qkv);
#pragma unroll
    for (int i = 0; i < 4; ++i)
        tile[ty + i*8][tx] = src[(size_t)(b*T_ + t0 + ty + i*8)*3072 + 2048 + h*64 + d0 + tx];
    __syncthreads();
    unsigned short* dst = reinterpret_cast<unsigned short*>(Vt);
#pragma unroll
    for (int i = 0; i < 4; ++i)
        dst[(size_t)(bh*64 + d0 + ty + i*8)*T_ + t0 + tx] = tile[tx][ty + i*8];
}

// ---------------- causal flash attention v5: paired q-tiles ----------------
__global__ __launch_bounds__(256)
void flash_attn(const bf16* __restrict__ qkv, const bf16* __restrict__ Vt,
                bf16* __restrict__ O) {
    __shared__ char smem[49152];
    int tid = threadIdx.x;
    int lane = tid & 63, w = tid >> 6;
    int lr = lane & 15, lq = lane >> 4;
    int bh = blockIdx.y, b = bh >> 4, h = bh & 15;
    int c = (int)((blockIdx.x + bh) & 15);
    int qtA = (bh & 16) ? (15 - c) : c;     // shallow 0..15
    int qtB = 31 - qtA;                     // deep 16..31
    int ntB = qtB + 1;
    int qwA = qtA*64 + w*16, qwB = qtB*64 + w*16;
    const bf16* Qb = qkv + (size_t)(b*T_)*3072 + h*HD_;
    const bf16* Kb = Qb + 1024;
    const bf16* Vb = Vt + (size_t)bh * HD_ * T_;
    char* PwA = smem + 32768 + w*2048;
    char* PwB = smem + 40960 + w*2048;

    int sc_   = (((lane & 7) ^ ((lane >> 3) & 7))) * 8;
    int srow_ = w*8 + (lane >> 3);

    s16x8 qfA[2], qfB[2];
#pragma unroll
    for (int kk = 0; kk < 2; ++kk) {
        qfA[kk] = *reinterpret_cast<const s16x8*>(Qb + (size_t)(qwA + lr)*3072 + kk*32 + lq*8);
        qfB[kk] = *reinterpret_cast<const s16x8*>(Qb + (size_t)(qwB + lr)*3072 + kk*32 + lq*8);
    }
    f32x4 odA[4] = {}, odB[4] = {};
    float mA = -1e30f, lA = 0.f, mB = -1e30f, lB = 0.f;
    const float SLOG2E = 0.125f * 1.44269504088896f;

    auto step = [&](f32x4 (&od)[4], float& mrun, float& lrun, char* Pw,
                    const s16x8 (&qf)[2], int qw, bool diag,
                    const char* Kt, const char* Vtl, int kv0) {
        f32x4 sc[4];
        __builtin_amdgcn_s_setprio(1);
#pragma unroll
        for (int n = 0; n < 4; ++n) {
            int row = n*16 + lr;
            int ko = row*128 + ((lq ^ (row & 7)) << 4);
            s16x8 kf0 = *reinterpret_cast<const s16x8*>(Kt + ko);
            s16x8 kf1 = *reinterpret_cast<const s16x8*>(Kt + (ko ^ 64));
            f32x4 z = {0.f, 0.f, 0.f, 0.f};
            z = MFMA16(kf0, qf[0], z);    // S^T: col=q(lr), row=kv
            z = MFMA16(kf1, qf[1], z);
            sc[n] = z;
        }
        __builtin_amdgcn_s_setprio(0);
        if (diag) {
            int q = qw + lr;
#pragma unroll
            for (int n = 0; n < 4; ++n)
#pragma unroll
                for (int r = 0; r < 4; ++r)
                    if (kv0 + n*16 + lq*4 + r > q) sc[n][r] = -1e30f;
        }
        float mx0 = fmaxf(fmaxf(sc[0][0], sc[0][1]), fmaxf(sc[0][2], sc[0][3]));
        float mx1 = fmaxf(fmaxf(sc[1][0], sc[1][1]), fmaxf(sc[1][2], sc[1][3]));
        float mx2 = fmaxf(fmaxf(sc[2][0], sc[2][1]), fmaxf(sc[2][2], sc[2][3]));
        float mx3 = fmaxf(fmaxf(sc[3][0], sc[3][1]), fmaxf(sc[3][2], sc[3][3]));
        float pmax = fmaxf(fmaxf(mx0, mx1), fmaxf(mx2, mx3));
        pmax = fmaxf(pmax, __shfl_xor(pmax, 16));
        pmax = fmaxf(pmax, __shfl_xor(pmax, 32));
        float ps = pmax * SLOG2E;
        if (__ballot(ps > mrun + 8.f)) {     // T13 defer-max
            float mn = fmaxf(mrun, ps);
            float corr = exp2f(mrun - mn);
            mrun = mn;
            lrun *= corr;
            float cR[4];
#pragma unroll
            for (int r = 0; r < 4; ++r) cR[r] = __shfl(corr, lq*4 + r);
#pragma unroll
            for (int nd = 0; nd < 4; ++nd)
#pragma unroll
                for (int r = 0; r < 4; ++r)
                    od[nd][r] *= cR[r];
        }
        float psum = 0.f;
#pragma unroll
        for (int n = 0; n < 4; ++n) {
            float p0 = exp2f(fmaf(sc[n][0], SLOG2E, -mrun));
            float p1 = exp2f(fmaf(sc[n][1], SLOG2E, -mrun));
            float p2 = exp2f(fmaf(sc[n][2], SLOG2E, -mrun));
            float p3 = exp2f(fmaf(sc[n][3], SLOG2E, -mrun));
            psum += (p0 + p1) + (p2 + p3);
            uint2 pk;
            pk.x = cvt_pk_bf16(p0, p1);
            pk.y = cvt_pk_bf16(p2, p3);
            int bo = (lr*128 + n*32 + lq*8) ^ ((lr & 7) << 4);
            *reinterpret_cast<uint2*>(Pw + bo) = pk;    // P[q=lr][kv]
        }
        psum += __shfl_xor(psum, 16);
        psum += __shfl_xor(psum, 32);
        lrun += psum;
        asm volatile("" ::: "memory");   // keep P stores before pa reads
        s16x8 pa[2];
#pragma unroll
        for (int kk = 0; kk < 2; ++kk) {
            int bo = (lr*128 + kk*64 + lq*16) ^ ((lr & 7) << 4);
            pa[kk] = *reinterpret_cast<const s16x8*>(Pw + bo);
        }
        __builtin_amdgcn_s_setprio(1);
#pragma unroll
        for (int nd = 0; nd < 4; ++nd) {
            int row = nd*16 + lr;
            int vo = row*128 + ((lq ^ (row & 7)) << 4);
            s16x8 vf0 = *reinterpret_cast<const s16x8*>(Vtl + vo);
            s16x8 vf1 = *reinterpret_cast<const s16x8*>(Vtl + (vo ^ 64));
            od[nd] = MFMA16(pa[0], vf0, od[nd]);
            od[nd] = MFMA16(pa[1], vf1, od[nd]);
        }
        __builtin_amdgcn_s_setprio(0);
    };

#define STAGE(bufi, tile) do {                                                          \
        int kv0s_ = (tile) * 64;                                                        \
        _Pragma("unroll")                                                               \
        for (int i_ = 0; i_ < 2; ++i_) {                                                \
            int rr_ = i_*32 + srow_;                                                    \
            async_cp16(Kb + (size_t)(kv0s_ + rr_)*3072 + sc_,                           \
                       smem + (bufi)*8192 + i_*4096 + w*1024);                          \
            async_cp16(Vb + (size_t)rr_*2048 + kv0s_ + sc_,                             \
                       smem + 16384 + (bufi)*8192 + i_*4096 + w*1024);                  \
        } } while (0)

    STAGE(0, 0);
    for (int it = 0; it < ntB; ++it) {
        int curb = it & 1;
        int kv0 = it * 64;
        if (it + 1 < ntB) {
            STAGE(curb ^ 1, it + 1);
            asm volatile("s_waitcnt vmcnt(4)" ::: "memory");
        } else {
            asm volatile("s_waitcnt vmcnt(0)" ::: "memory");
        }
        __builtin_amdgcn_sched_barrier(0);
        __builtin_amdgcn_s_barrier();
        __builtin_amdgcn_sched_barrier(0);
        const char* Kt = smem + curb*8192;
        const char* Vtl = smem + 16384 + curb*8192;
        step(odB, mB, lB, PwB, qfB, qwB, it == qtB, Kt, Vtl, kv0);
        if (it <= qtA)
            step(odA, mA, lA, PwA, qfA, qwA, it == qtA, Kt, Vtl, kv0);
        __builtin_amdgcn_sched_barrier(0);
        __builtin_amdgcn_s_barrier();   // reads done before next STAGE overwrites
        __builtin_amdgcn_sched_barrier(0);
    }
#undef STAGE
    float lRA[4], lRB[4];
#pragma unroll
    for (int r = 0; r < 4; ++r) {
        lRA[r] = 1.0f / __shfl(lA, lq*4 + r);
        lRB[r] = 1.0f / __shfl(lB, lq*4 + r);
    }
#pragma unroll
    for (int nd = 0; nd < 4; ++nd) {
#pragma unroll
        for (int r = 0; r < 4; ++r) {
            int rowA = qwA + lq*4 + r;
            int rowB = qwB + lq*4 + r;
            int col = h*HD_ + nd*16 + lr;
            O[(size_t)(b*T_ + rowA)*E_ + col] = __float2bfloat16(odA[nd][r] * lRA[r]);
            O[(size_t)(b*T_ + rowB)*E_ + col] = __float2bfloat16(odB[nd][r] * lRB[r]);
        }
    }
}

// ---------------- launch ----------------
extern "C" void kernel_launch(void* const* d_in, const int* in_sizes, int n_in,
                              void* d_out, int out_size, void* d_ws, size_t ws_size,
                              hipStream_t stream) {
    const float* x   = (const float*)d_in[0];
    const float* Wk  = (const float*)d_in[1];
    const float* Wq  = (const float*)d_in[2];
    const float* Wv  = (const float*)d_in[3];
    const float* Wp  = (const float*)d_in[4];
    const float* bp  = (const float*)d_in[5];
    const float* W1  = (const float*)d_in[6];
    const float* b1  = (const float*)d_in[7];
    const float* W2  = (const float*)d_in[8];
    const float* b2  = (const float*)d_in[9];
    const float* g1  = (const float*)d_in[10];
    const float* be1 = (const float*)d_in[11];
    const float* g2  = (const float*)d_in[12];
    const float* be2 = (const float*)d_in[13];
    float* out = (float*)d_out;

    char* ws = (char*)d_ws;
    bf16* Wqkv_t = (bf16*)(ws + 0);          //  6 MB [3072][1024] (+Wp_t after)
    bf16* Wp_t   = (bf16*)(ws + 6291456);    //  2 MB [1024][1024]
    bf16* W1_t   = (bf16*)(ws + 8388608);    //  8 MB [4096][1024]
    bf16* W2_t   = (bf16*)(ws + 16777216);   //  8 MB [1024][4096]
    bf16* h      = (bf16*)(ws + 25165824);   //  8 MB [4096][1024] (reused as h2)
    bf16* qkv    = (bf16*)(ws + 33554432);   // 24 MB [4096][3072]
    bf16* Vt     = (bf16*)(ws + 58720256);   //  8 MB [B,H,HD,T]
    bf16* attnO  = (bf16*)(ws + 67108864);   //  8 MB [4096][1024]
    bf16* ff1    = (bf16*)(ws + 33554432);   // 32 MB, reuses qkv+Vt (dead after flash)
    float* x2    = (ws_size >= 92274688) ? (float*)(ws + 75497472) : out;  // 16 MB

    dim3 tb(32, 8);
    transpose_all<<<12288, tb, 0, stream>>>(Wq, Wk, Wv, Wp, W1, W2, Wqkv_t, W1_t, W2_t);

    ln_kernel<<<NT, 256, 0, stream>>>(x, g1, be1, h);
    gemm_t<128,0><<<dim3(24, 32), 256, 0, stream>>>(h, Wqkv_t, qkv, nullptr, nullptr, NT, 3072, 1024);
    v_transpose<<<dim3(64, 2, 32), tb, 0, stream>>>(qkv, Vt);
    flash_attn<<<dim3(16, 32), 256, 0, stream>>>(qkv, Vt, attnO);
    gemm_t<64,1><<<dim3(16, 32), 256, 0, stream>>>(attnO, Wp_t, x2, bp, x, NT, 1024, 1024);
    ln_kernel<<<NT, 256, 0, stream>>>(x2, g2, be2, h);
    gemm_t<128,2><<<dim3(32, 32), 256, 0, stream>>>(h, W1_t, ff1, b1, nullptr, NT, 4096, 1024);
    gemm_t<64,1><<<dim3(16, 32), 256, 0, stream>>>(ff1, W2_t, out, b2, x2, NT, 1024, 4096);
}